// Round 6
// baseline (418.909 us; speedup 1.0000x reference)
//
#include <hip/hip_runtime.h>
#include <hip/hip_bf16.h>
#include <cstdint>

// ============================================================================
// MoE transformer layer, MI355X gfx950.
// Precision: upstream of the router (LN1, QK, attention scores, WO, LN2,
// logits) is ~fp32 via split-bf16 MFMA (3-pass); V path plain bf16; logits
// exact fp32; expert GEMM plain bf16; routed MoE via ballot-compacted lists.
// R10: swapped QK^T (A=K,B=Q) register-P attention, own-quad sigma PV, plain
// bf16 V (gemm_v, quad-swizzled transposed output), split QK accumulator.
// R11 (attn load balance — occupancy was pinned at 13.5% of 25% cap across
// R5/R9/R10 while per-block work removal did nothing):
//   - attention grid = 1280 near-uniform KEY-CHUNK blocks (<=8 key-tiles
//     each), table-driven, heavy-first (LPT). 2.5x oversubscribed at
//     3 blocks/CU (LDS 48KB, launch_bounds(256,3)).
//   - O,l are pure sums -> chunk partials combine via f32 atomicAdd into
//     O_acc[4096][1024] / L_acc[4096][16] (hipMemsetAsync-zeroed).
//   - attn_final normalizes and emits split-bf16 a_hi/a_lo for WO.
// ============================================================================

typedef __bf16 bf16;
typedef __bf16 bf16x8 __attribute__((ext_vector_type(8)));
typedef __bf16 bf16x4 __attribute__((ext_vector_type(4)));
typedef float f32x4 __attribute__((ext_vector_type(4)));
typedef float f32x16 __attribute__((ext_vector_type(16)));

#define MFMA(a, b, c) __builtin_amdgcn_mfma_f32_16x16x32_bf16(a, b, c, 0, 0, 0)
#define MFMA32(a, b, c) __builtin_amdgcn_mfma_f32_32x32x16_bf16(a, b, c, 0, 0, 0)

__device__ __forceinline__ void gld16(void* lds, const void* g) {
  __builtin_amdgcn_global_load_lds(
      (const __attribute__((address_space(1))) void*)g,
      (__attribute__((address_space(3))) void*)lds, 16, 0, 0);
}

// ---------------------------------------------------------------------------
// Fused weight prep: split wq/wk/wv/wo into (hi,lo) bf16; cvt expw to bf16.
// blocks 0..4095: splits (1024 per weight); 4096..12287: expert cvt.
// ---------------------------------------------------------------------------
__global__ void prep_weights(const float* __restrict__ wq, const float* __restrict__ wk,
                             const float* __restrict__ wv, const float* __restrict__ wo,
                             const float* __restrict__ expw,
                             bf16* __restrict__ wqh, bf16* __restrict__ wql,
                             bf16* __restrict__ wkh, bf16* __restrict__ wkl,
                             bf16* __restrict__ wvh, bf16* __restrict__ wvl,
                             bf16* __restrict__ woh, bf16* __restrict__ wol,
                             bf16* __restrict__ ewh) {
  int bid = blockIdx.x;
  if (bid < 4096) {
    int wsel = bid >> 10;
    const float* src = wsel == 0 ? wq : wsel == 1 ? wk : wsel == 2 ? wv : wo;
    bf16* hi = wsel == 0 ? wqh : wsel == 1 ? wkh : wsel == 2 ? wvh : woh;
    bf16* lo = wsel == 0 ? wql : wsel == 1 ? wkl : wsel == 2 ? wvl : wol;
    int i = ((bid & 1023) * 256 + threadIdx.x) * 4;
    float4 v = *(const float4*)(src + i);
    float a[4] = {v.x, v.y, v.z, v.w};
#pragma unroll
    for (int j = 0; j < 4; j++) {
      bf16 h = (bf16)a[j];
      hi[i + j] = h;
      lo[i + j] = (bf16)(a[j] - (float)h);
    }
  } else {
    int i = ((bid - 4096) * 256 + threadIdx.x) * 4;
    float4 v = *(const float4*)(expw + i);
    ewh[i] = (bf16)v.x; ewh[i + 1] = (bf16)v.y;
    ewh[i + 2] = (bf16)v.z; ewh[i + 3] = (bf16)v.w;
  }
}

// ---------------------------------------------------------------------------
__global__ void ln_split(const float* __restrict__ x, const float* __restrict__ g,
                         const float* __restrict__ b, bf16* __restrict__ hi,
                         bf16* __restrict__ lo) {
  int tok = blockIdx.x, t = threadIdx.x;
  float4 v = ((const float4*)(x + (size_t)tok * 1024))[t];
  float s = v.x + v.y + v.z + v.w;
  float ss = v.x * v.x + v.y * v.y + v.z * v.z + v.w * v.w;
#pragma unroll
  for (int o = 1; o < 64; o <<= 1) { s += __shfl_xor(s, o); ss += __shfl_xor(ss, o); }
  __shared__ float red[8];
  int w = t >> 6, lane = t & 63;
  if (lane == 0) { red[w] = s; red[4 + w] = ss; }
  __syncthreads();
  s = red[0] + red[1] + red[2] + red[3];
  ss = red[4] + red[5] + red[6] + red[7];
  float mu = s * (1.f / 1024.f);
  float rstd = rsqrtf(ss * (1.f / 1024.f) - mu * mu + 1e-5f);
  float4 gv = ((const float4*)g)[t], bv = ((const float4*)b)[t];
  float y[4] = {(v.x - mu) * rstd * gv.x + bv.x, (v.y - mu) * rstd * gv.y + bv.y,
                (v.z - mu) * rstd * gv.z + bv.z, (v.w - mu) * rstd * gv.w + bv.w};
  size_t o = (size_t)tok * 1024 + t * 4;
#pragma unroll
  for (int j = 0; j < 4; j++) {
    bf16 h = (bf16)y[j];
    hi[o + j] = h;
    lo[o + j] = (bf16)(y[j] - (float)h);
  }
}

// ---------------------------------------------------------------------------
// Fused LN2 + router: exact fp32 logits from LDS h2, top-2, gates. No atomics.
// Also emits h2 bf16 (expert GEMM A operand).
// ---------------------------------------------------------------------------
__global__ void ln2route(const float* __restrict__ x1, const float* __restrict__ g,
                         const float* __restrict__ b, const float* __restrict__ rw,
                         bf16* __restrict__ h2h, int* __restrict__ eid,
                         float2* __restrict__ gout) {
  int tok = blockIdx.x, t = threadIdx.x;
  float4 v = ((const float4*)(x1 + (size_t)tok * 1024))[t];
  float s = v.x + v.y + v.z + v.w;
  float ss = v.x * v.x + v.y * v.y + v.z * v.z + v.w * v.w;
#pragma unroll
  for (int o = 1; o < 64; o <<= 1) { s += __shfl_xor(s, o); ss += __shfl_xor(ss, o); }
  __shared__ float red[8];
  __shared__ float h2s[1024];
  __shared__ float lg[8];
  int w = t >> 6, lane = t & 63;
  if (lane == 0) { red[w] = s; red[4 + w] = ss; }
  __syncthreads();
  s = red[0] + red[1] + red[2] + red[3];
  ss = red[4] + red[5] + red[6] + red[7];
  float mu = s * (1.f / 1024.f);
  float rstd = rsqrtf(ss * (1.f / 1024.f) - mu * mu + 1e-5f);
  float4 gv = ((const float4*)g)[t], bv = ((const float4*)b)[t];
  float4 y;
  y.x = (v.x - mu) * rstd * gv.x + bv.x;
  y.y = (v.y - mu) * rstd * gv.y + bv.y;
  y.z = (v.z - mu) * rstd * gv.z + bv.z;
  y.w = (v.w - mu) * rstd * gv.w + bv.w;
  ((float4*)h2s)[t] = y;
  size_t o = (size_t)tok * 1024 + t * 4;
  h2h[o] = (bf16)y.x; h2h[o + 1] = (bf16)y.y;
  h2h[o + 2] = (bf16)y.z; h2h[o + 3] = (bf16)y.w;
  __syncthreads();
  float a0 = 0.f, a1 = 0.f;
  const float4* r0 = (const float4*)(rw + (2 * w) * 1024);
  const float4* r1 = (const float4*)(rw + (2 * w + 1) * 1024);
#pragma unroll
  for (int it = 0; it < 4; it++) {
    float4 xv = ((const float4*)h2s)[lane + 64 * it];
    float4 w0 = r0[lane + 64 * it];
    float4 w1 = r1[lane + 64 * it];
    a0 += xv.x * w0.x + xv.y * w0.y + xv.z * w0.z + xv.w * w0.w;
    a1 += xv.x * w1.x + xv.y * w1.y + xv.z * w1.z + xv.w * w1.w;
  }
#pragma unroll
  for (int o2 = 1; o2 < 64; o2 <<= 1) {
    a0 += __shfl_xor(a0, o2);
    a1 += __shfl_xor(a1, o2);
  }
  if (lane == 0) { lg[2 * w] = a0; lg[2 * w + 1] = a1; }
  __syncthreads();
  if (t == 0) {
    int i0 = 0; float l0 = lg[0];
#pragma unroll
    for (int e = 1; e < 8; e++) if (lg[e] > l0) { l0 = lg[e]; i0 = e; }
    int i1 = -1; float l1 = -3e38f;
#pragma unroll
    for (int e = 0; e < 8; e++) if (e != i0 && lg[e] > l1) { l1 = lg[e]; i1 = e; }
    float e1 = __expf(l1 - l0);
    float den = 1.f + e1;
    eid[tok] = i0 | (i1 << 4);
    gout[tok] = make_float2(1.f / den, e1 / den);
  }
}

// ---------------------------------------------------------------------------
// Per-expert compaction: 8 blocks, ballot + popcount prefix scan, token order.
// ---------------------------------------------------------------------------
__global__ void build_lists(const int* __restrict__ eid,
                            const float2* __restrict__ gv,
                            int* __restrict__ tlist, float* __restrict__ glist,
                            int* __restrict__ cnt) {
  int e = blockIdx.x, t = threadIdx.x;
  int lane = t & 63, w = t >> 6;
  __shared__ int wt[4];
  int base = 0;
  for (int c = 0; c < 16; c++) {
    int tok = c * 256 + t;
    int pair = eid[tok];
    int e0 = pair & 15, e1 = pair >> 4;
    bool p = (e0 == e) || (e1 == e);
    float2 g2 = gv[tok];
    float gate = (e0 == e) ? g2.x : g2.y;
    unsigned long long m = __ballot(p);
    int rank = __popcll(m & ((1ull << lane) - 1ull));
    if (lane == 0) wt[w] = __popcll(m);
    __syncthreads();
    int off = base;
    for (int i = 0; i < w; i++) off += wt[i];
    if (p) {
      tlist[e * 4096 + off + rank] = tok;
      glist[e * 4096 + off + rank] = gate;
    }
    base += wt[0] + wt[1] + wt[2] + wt[3];
    __syncthreads();
  }
  if (t == 0) cnt[e] = base;
  int pad = (base + 127) & ~127;
  if (pad > 4096) pad = 4096;
  for (int i = base + t; i < pad; i += 256) {
    tlist[e * 4096 + i] = 0;
    glist[e * 4096 + i] = 0.f;
  }
}

// ---------------------------------------------------------------------------
// Split-bf16 NT GEMM core: C(128x128 fp32) = (Ah+Al) @ (Bh+Bl)^T, K=1024.
// ---------------------------------------------------------------------------
__device__ __forceinline__ void gemm_core_split(
    const bf16* __restrict__ Ah, const bf16* __restrict__ Al,
    const bf16* __restrict__ Bh, const bf16* __restrict__ Bl, int m0, int n0,
    f32x4 (&acc)[4][4]) {
  __shared__ __align__(16) bf16 As_h[4096], As_l[4096], Bs_h[4096], Bs_l[4096];
  int t = threadIdx.x, lane = t & 63, w = t >> 6;
  int i0 = t, i1 = t + 256;
  const bf16* a0h = Ah + (size_t)(m0 + (i0 >> 2)) * 1024 + (i0 & 3) * 8;
  const bf16* a1h = Ah + (size_t)(m0 + (i1 >> 2)) * 1024 + (i1 & 3) * 8;
  const bf16* a0l = Al + (size_t)(m0 + (i0 >> 2)) * 1024 + (i0 & 3) * 8;
  const bf16* a1l = Al + (size_t)(m0 + (i1 >> 2)) * 1024 + (i1 & 3) * 8;
  const bf16* b0h = Bh + (size_t)(n0 + (i0 >> 2)) * 1024 + (i0 & 3) * 8;
  const bf16* b1h = Bh + (size_t)(n0 + (i1 >> 2)) * 1024 + (i1 & 3) * 8;
  const bf16* b0l = Bl + (size_t)(n0 + (i0 >> 2)) * 1024 + (i0 & 3) * 8;
  const bf16* b1l = Bl + (size_t)(n0 + (i1 >> 2)) * 1024 + (i1 & 3) * 8;
  int wm = (w >> 1) * 64, wn = (w & 1) * 64;
  int lr = lane & 15, lq = lane >> 4;
  for (int k0 = 0; k0 < 1024; k0 += 32) {
    __syncthreads();
    gld16(&As_h[i0 * 8], a0h + k0); gld16(&As_h[i1 * 8], a1h + k0);
    gld16(&As_l[i0 * 8], a0l + k0); gld16(&As_l[i1 * 8], a1l + k0);
    gld16(&Bs_h[i0 * 8], b0h + k0); gld16(&Bs_h[i1 * 8], b1h + k0);
    gld16(&Bs_l[i0 * 8], b0l + k0); gld16(&Bs_l[i1 * 8], b1l + k0);
    __syncthreads();
    bf16x8 ah[4], al4[4], bh[4], bl4[4];
#pragma unroll
    for (int i = 0; i < 4; i++) {
      ah[i]  = *(const bf16x8*)&As_h[(wm + i * 16 + lr) * 32 + lq * 8];
      al4[i] = *(const bf16x8*)&As_l[(wm + i * 16 + lr) * 32 + lq * 8];
      bh[i]  = *(const bf16x8*)&Bs_h[(wn + i * 16 + lr) * 32 + lq * 8];
      bl4[i] = *(const bf16x8*)&Bs_l[(wn + i * 16 + lr) * 32 + lq * 8];
    }
#pragma unroll
    for (int i = 0; i < 4; i++)
#pragma unroll
      for (int j = 0; j < 4; j++) {
        f32x4 c = acc[i][j];
        c = MFMA(ah[i], bh[j], c);
        c = MFMA(ah[i], bl4[j], c);
        c = MFMA(al4[i], bh[j], c);
        acc[i][j] = c;
      }
  }
}

// Q/K projections (split-bf16, 3-pass). z==0 (Q) pre-scaled into exp2 domain.
__global__ __launch_bounds__(256, 2) void gemm_qk(
    const bf16* __restrict__ hh, const bf16* __restrict__ hl,
    const bf16* __restrict__ wqh, const bf16* __restrict__ wql,
    const bf16* __restrict__ wkh, const bf16* __restrict__ wkl,
    bf16* __restrict__ qh, bf16* __restrict__ ql, bf16* __restrict__ kh,
    bf16* __restrict__ kl) {
  int n0 = blockIdx.x * 128, m0 = blockIdx.y * 128, z = blockIdx.z;
  const bf16* Bh = z ? wkh : wqh;
  const bf16* Bl = z ? wkl : wql;
  f32x4 acc[4][4];
#pragma unroll
  for (int i = 0; i < 4; i++)
#pragma unroll
    for (int j = 0; j < 4; j++) acc[i][j] = (f32x4){0.f, 0.f, 0.f, 0.f};
  gemm_core_split(hh, hl, Bh, Bl, m0, n0, acc);
  int t = threadIdx.x, lane = t & 63, w = t >> 6;
  int wm = (w >> 1) * 64, wn = (w & 1) * 64, lr = lane & 15, lq = lane >> 4;
  bf16* Oh = z ? kh : qh;
  bf16* Ol = z ? kl : ql;
  float scale = z ? 1.0f : (0.125f * 1.44269504f);
#pragma unroll
  for (int i = 0; i < 4; i++)
#pragma unroll
    for (int j = 0; j < 4; j++)
#pragma unroll
      for (int r = 0; r < 4; r++) {
        size_t row = m0 + wm + i * 16 + lq * 4 + r;
        int col = n0 + wn + j * 16 + lr;
        float v = acc[i][j][r] * scale;
        bf16 h = (bf16)v;
        Oh[row * 1024 + col] = h;
        Ol[row * 1024 + col] = (bf16)(v - (float)h);
      }
}

// V projection: PLAIN bf16 single-pass. Output written DIRECTLY TRANSPOSED to
// vt[(b*16+head)*64+d][s] AND quad-swizzled within each 64-token chunk:
// physical quad = logical quad ^ (d&15). Attn's 8B sigma-reads alias at most
// 2-way (free) while gld16 staging stays linear.
__global__ __launch_bounds__(256, 2) void gemm_v(
    const bf16* __restrict__ A, const bf16* __restrict__ B,
    bf16* __restrict__ vth) {
  int n0 = blockIdx.x * 128, m0 = blockIdx.y * 128;
  __shared__ __align__(16) bf16 As[4096], Bs[4096];
  int t = threadIdx.x, lane = t & 63, w = t >> 6;
  int i0 = t, i1 = t + 256;
  const bf16* a0 = A + (size_t)(m0 + (i0 >> 2)) * 1024 + (i0 & 3) * 8;
  const bf16* a1 = A + (size_t)(m0 + (i1 >> 2)) * 1024 + (i1 & 3) * 8;
  const bf16* b0 = B + (size_t)(n0 + (i0 >> 2)) * 1024 + (i0 & 3) * 8;
  const bf16* b1 = B + (size_t)(n0 + (i1 >> 2)) * 1024 + (i1 & 3) * 8;
  int wm = (w >> 1) * 64, wn = (w & 1) * 64, lr = lane & 15, lq = lane >> 4;
  f32x4 acc[4][4];
#pragma unroll
  for (int i = 0; i < 4; i++)
#pragma unroll
    for (int j = 0; j < 4; j++) acc[i][j] = (f32x4){0.f, 0.f, 0.f, 0.f};
  for (int k0 = 0; k0 < 1024; k0 += 32) {
    __syncthreads();
    gld16(&As[i0 * 8], a0 + k0); gld16(&As[i1 * 8], a1 + k0);
    gld16(&Bs[i0 * 8], b0 + k0); gld16(&Bs[i1 * 8], b1 + k0);
    __syncthreads();
    bf16x8 af[4], bfr[4];
#pragma unroll
    for (int i = 0; i < 4; i++) {
      af[i] = *(const bf16x8*)&As[(wm + i * 16 + lr) * 32 + lq * 8];
      bfr[i] = *(const bf16x8*)&Bs[(wn + i * 16 + lr) * 32 + lq * 8];
    }
#pragma unroll
    for (int i = 0; i < 4; i++)
#pragma unroll
      for (int j = 0; j < 4; j++) acc[i][j] = MFMA(af[i], bfr[j], acc[i][j]);
  }
  int bb = m0 >> 11;           // batch index (128-row tile never crosses)
  int srow0 = m0 & 2047;
#pragma unroll
  for (int i = 0; i < 4; i++)
#pragma unroll
    for (int j = 0; j < 4; j++) {
      int col = n0 + wn + j * 16 + lr;  // dim in [0,1024)
      int head = col >> 6, d = col & 63;
      int s = srow0 + wm + i * 16 + lq * 4;  // quad-aligned token index
      // quad swizzle within 64-token chunk: pq = lq ^ (d&15)
      int ss = (s & ~63) | (((((s >> 2) & 15)) ^ (d & 15)) << 2);
      bf16x4 hv;
#pragma unroll
      for (int r = 0; r < 4; r++) hv[r] = (bf16)acc[i][j][r];
      size_t off = ((size_t)((bb * 16 + head) * 64 + d)) * 2048 + ss;
      *(bf16x4*)(vth + off) = hv;
    }
}

// WO projection + residual: out_f32 = x + attn @ wo^T
__global__ __launch_bounds__(256, 2) void gemm_wo(
    const bf16* __restrict__ ah, const bf16* __restrict__ al,
    const bf16* __restrict__ bh, const bf16* __restrict__ bl,
    const float* __restrict__ resid, float* __restrict__ outp) {
  int n0 = blockIdx.x * 128, m0 = blockIdx.y * 128;
  f32x4 acc[4][4];
#pragma unroll
  for (int i = 0; i < 4; i++)
#pragma unroll
    for (int j = 0; j < 4; j++) acc[i][j] = (f32x4){0.f, 0.f, 0.f, 0.f};
  gemm_core_split(ah, al, bh, bl, m0, n0, acc);
  int t = threadIdx.x, lane = t & 63, w = t >> 6;
  int wm = (w >> 1) * 64, wn = (w & 1) * 64, lr = lane & 15, lq = lane >> 4;
#pragma unroll
  for (int i = 0; i < 4; i++)
#pragma unroll
    for (int j = 0; j < 4; j++)
#pragma unroll
      for (int r = 0; r < 4; r++) {
        size_t row = m0 + wm + i * 16 + lq * 4 + r;
        int col = n0 + wn + j * 16 + lr;
        outp[row * 1024 + col] = resid[row * 1024 + col] + acc[i][j][r];
      }
}

// ---------------------------------------------------------------------------
// Flash attention (R11: key-chunked, atomic combine). Compute core identical
// to R10: swapped QK^T (A=K,B=Q), register-P, own-quad sigma PV, plain-bf16 V
// (pre-swizzled), split QK accumulator, K/V double-buffered 2-phase staging.
// Grid = (32 hb, 40 chunk-items); each item = (qt, key-tiles [t0,t1)), <=8
// tiles, heavy-first (LPT). O,l partials are pure sums -> atomicAdd into
// O_acc[tok][1024] / L_acc[tok][16]. 3 blocks/CU (LDS 48KB).
// ---------------------------------------------------------------------------
__global__ __launch_bounds__(256, 3) void attn_fused(
    const bf16* __restrict__ qh, const bf16* __restrict__ ql,
    const bf16* __restrict__ kh, const bf16* __restrict__ kl,
    const bf16* __restrict__ vth,
    float* __restrict__ O_acc, float* __restrict__ L_acc) {
  const int S = 2048, D = 1024;
  // work table: y -> (qt, tile range [t0,t1)); 28 full-8 chunks first, then
  // remainders descending (6,6,6,6, 4,4,4,4, 2,2,2,2). Sum of lens = 272.
  static const unsigned char QTt[40] = {
      15, 15, 15, 15, 14, 14, 14, 13, 13, 13, 12, 12, 12, 11, 11, 11,
      10, 10, 9, 9, 8, 8, 7, 7, 6, 5, 4, 3,
      14, 10, 6, 2, 13, 9, 5, 1, 12, 8, 4, 0};
  static const unsigned char C0t[40] = {
      0, 8, 16, 24, 0, 8, 16, 0, 8, 16, 0, 8, 16, 0, 8, 16,
      0, 8, 0, 8, 0, 8, 0, 8, 0, 0, 0, 0,
      24, 16, 8, 0, 24, 16, 8, 0, 24, 16, 8, 0};
  static const unsigned char C1t[40] = {
      8, 16, 24, 32, 8, 16, 24, 8, 16, 24, 8, 16, 24, 8, 16, 24,
      8, 16, 8, 16, 8, 16, 8, 16, 8, 8, 8, 8,
      30, 22, 14, 6, 28, 20, 12, 4, 26, 18, 10, 2};
  int y = blockIdx.y;
  int qt = QTt[y];
  int tile0 = C0t[y], tile1 = C1t[y];
  int hb = blockIdx.x;
  int head = hb & 15, b = hb >> 4;
  int qb = qt * 128;
  int t = threadIdx.x, lane = t & 63, w = t >> 6;
  int l31 = lane & 31, l5 = lane >> 5;
  int base = b * S, hcol = head * 64;

  __shared__ __align__(16) bf16 Kh_s[2][4096], Kl_s[2][4096];  // [key64][d64] swz
  __shared__ __align__(16) bf16 Vh_s[2][4096];                 // [d64][key64] quad-swz

  // Q B-frags (swapped: B[k=d][n=q], lane n=l31=q, k chunk c: d=16c+l5*8+j)
  bf16x8 qfh[4], qfl[4];
  {
    const bf16* p1 = qh + (size_t)(base + qb + w * 32 + l31) * D + hcol + l5 * 8;
    const bf16* p2 = ql + (size_t)(base + qb + w * 32 + l31) * D + hcol + l5 * 8;
#pragma unroll
    for (int c = 0; c < 4; c++) {
      qfh[c] = *(const bf16x8*)(p1 + 16 * c);
      qfl[c] = *(const bf16x8*)(p2 + 16 * c);
    }
  }
  f32x16 O0, O1;
  float lsum = 0.f;
#pragma unroll
  for (int r = 0; r < 16; r++) { O0[r] = 0.f; O1[r] = 0.f; }

  // staging: slot s in {t, t+256}: row = s>>3 (r1 = r0+32, same &7), phys
  // group p = t&7; K data group g = p ^ (row&7); V is linear (pre-swizzled).
  int r0 = t >> 3, p0 = t & 7;
  int g0 = p0 ^ (r0 & 7);
  const bf16* k0hp = kh + (size_t)(base + r0) * D + hcol + g0 * 8;
  const bf16* k1hp = kh + (size_t)(base + 32 + r0) * D + hcol + g0 * 8;
  const bf16* k0lp = kl + (size_t)(base + r0) * D + hcol + g0 * 8;
  const bf16* k1lp = kl + (size_t)(base + 32 + r0) * D + hcol + g0 * 8;
  const bf16* v0hp = vth + (size_t)(hb * 64 + r0) * 2048 + p0 * 8;
  const bf16* v1hp = vth + (size_t)(hb * 64 + 32 + r0) * 2048 + p0 * 8;

  int qwmin = qb + w * 32;

#define STAGE(kts, bb) do { \
    gld16(&Kh_s[bb][t * 8], k0hp + (size_t)(kts) * D); \
    gld16(&Kh_s[bb][2048 + t * 8], k1hp + (size_t)(kts) * D); \
    gld16(&Kl_s[bb][t * 8], k0lp + (size_t)(kts) * D); \
    gld16(&Kl_s[bb][2048 + t * 8], k1lp + (size_t)(kts) * D); \
    gld16(&Vh_s[bb][t * 8], v0hp + (kts)); \
    gld16(&Vh_s[bb][2048 + t * 8], v1hp + (kts)); \
  } while (0)

  STAGE(tile0 * 64, tile0 & 1);
  __syncthreads();

  for (int ti = tile0; ti < tile1; ++ti) {
    int kt = ti * 64;
    int bb = ti & 1;
    if (ti + 1 < tile1) STAGE((ti + 1) * 64, bb ^ 1);   // prefetch next tile
    if (kt <= qwmin + 31) {
      bool skip1 = (kt + 32 > qwmin + 31);           // upper 32 keys all masked
#pragma unroll
      for (int ktile = 0; ktile < 2; ktile++) {
        if (ktile == 1 && skip1) break;
        bool maskt = (kt + 32 * ktile + 31 > qwmin);
        int keyr = ktile * 32 + l31;
        f32x16 scA, scB;
#pragma unroll
        for (int r = 0; r < 16; r++) { scA[r] = 0.f; scB[r] = 0.f; }
        __builtin_amdgcn_s_setprio(1);
#pragma unroll
        for (int c = 0; c < 4; c++) {
          int dg = ((2 * c + l5) ^ (keyr & 7)) * 8;
          bf16x8 kv = *(const bf16x8*)&Kh_s[bb][keyr * 64 + dg];
          bf16x8 km = *(const bf16x8*)&Kl_s[bb][keyr * 64 + dg];
          if (c < 2) {                    // chain A (compile-time split)
            scA = MFMA32(kv, qfh[c], scA);
            scA = MFMA32(kv, qfl[c], scA);
            scA = MFMA32(km, qfh[c], scA);
          } else {                        // chain B
            scB = MFMA32(kv, qfh[c], scB);
            scB = MFMA32(kv, qfl[c], scB);
            scB = MFMA32(km, qfh[c], scB);
          }
        }
        __builtin_amdgcn_s_setprio(0);
        // lane holds S[q=l31][key = kt+32*ktile+crow(r)], crow=(r&3)+8(r>>2)+4l5
        int kb0 = kt + 32 * ktile + 4 * l5;
        int qg = qwmin + l31;
        float pvv[16];
#pragma unroll
        for (int r = 0; r < 16; r++) {
          int cst = (r & 3) + 8 * (r >> 2);
          float sv = scA[r] + scB[r];
          if (maskt && (kb0 + cst > qg)) sv = -30000.f;
          float p = __builtin_amdgcn_exp2f(sv);
          pvv[r] = p;
          lsum += p;
        }
        // pack hi/lo bf16 pairs: hw[o][j] = keys {8o+2j+4*l5, +1} of this tile
        uint32_t hw[4][2], lw[4][2];
#pragma unroll
        for (int o = 0; o < 4; o++)
#pragma unroll
          for (int j = 0; j < 2; j++) {
            int ra = 4 * o + 2 * j;
            bf16 h0 = (bf16)pvv[ra], h1 = (bf16)pvv[ra + 1];
            union { bf16 h[2]; uint32_t u; } ph, pl;
            ph.h[0] = h0; ph.h[1] = h1;
            pl.h[0] = (bf16)(pvv[ra] - (float)h0);
            pl.h[1] = (bf16)(pvv[ra + 1] - (float)h1);
            hw[o][j] = ph.u;
            lw[o][j] = pl.u;
          }
        // ---- PV per 16-key chunk with own-quad sigma (no cross-lane) ----
#pragma unroll
        for (int c2 = 0; c2 < 2; c2++) {
          union { uint32_t u[4]; bf16x8 v; } pa, plo;
          pa.u[0] = hw[2 * c2][0];     pa.u[1] = hw[2 * c2][1];
          pa.u[2] = hw[2 * c2 + 1][0]; pa.u[3] = hw[2 * c2 + 1][1];
          plo.u[0] = lw[2 * c2][0];     plo.u[1] = lw[2 * c2][1];
          plo.u[2] = lw[2 * c2 + 1][0]; plo.u[3] = lw[2 * c2 + 1][1];
          __builtin_amdgcn_s_setprio(1);
#pragma unroll
          for (int dtile = 0; dtile < 2; dtile++) {
            int d = dtile * 32 + l31;
            // logical quad L = 8*ktile+4*c2+l5 (bit1 == 0 -> partner = pq^2)
            int pqA = ((8 * ktile + 4 * c2 + l5) ^ (d & 15)) * 4;
            union { bf16x4 q[2]; bf16x8 v; } vbu;
            vbu.q[0] = *(const bf16x4*)&Vh_s[bb][d * 64 + pqA];
            vbu.q[1] = *(const bf16x4*)&Vh_s[bb][d * 64 + (pqA ^ 8)];
            if (dtile == 0) {
              O0 = MFMA32(pa.v, vbu.v, O0);
              O0 = MFMA32(plo.v, vbu.v, O0);
            } else {
              O1 = MFMA32(pa.v, vbu.v, O1);
              O1 = MFMA32(plo.v, vbu.v, O1);
            }
          }
          __builtin_amdgcn_s_setprio(0);
        }
      }
    }
    __syncthreads();
  }
#undef STAGE
  // ---- epilogue: atomic combine of chunk partials (pure sums) ----
  if (tile0 * 64 <= qwmin + 31) {        // wave contributed something
    float ltot = lsum + __shfl_xor(lsum, 32);   // l(q=l31), both halves
    if (l5 == 0) {
      size_t tokq = (size_t)(base + qb + w * 32 + l31);
      atomicAdd(&L_acc[tokq * 16 + head], ltot);
    }
#pragma unroll
    for (int r = 0; r < 16; r++) {
      int qlocal = (r & 3) + 8 * (r >> 2) + 4 * l5;
      size_t tok = (size_t)(base + qb + w * 32 + qlocal);
      atomicAdd(&O_acc[tok * 1024 + hcol + l31], O0[r]);
      atomicAdd(&O_acc[tok * 1024 + hcol + 32 + l31], O1[r]);
    }
  }
}

// ---------------------------------------------------------------------------
// Attention finalize: O = O_acc / l, emit split-bf16 for WO GEMM.
// ---------------------------------------------------------------------------
__global__ void attn_final(const float* __restrict__ O_acc,
                           const float* __restrict__ L_acc,
                           bf16* __restrict__ oh, bf16* __restrict__ ol) {
  int tok = blockIdx.x, t = threadIdx.x;
  float4 v = ((const float4*)(O_acc + (size_t)tok * 1024))[t];
  float linv = 1.f / L_acc[tok * 16 + (t >> 4)];   // head = (4t)>>6 = t>>4
  float a[4] = {v.x * linv, v.y * linv, v.z * linv, v.w * linv};
  bf16x4 hv, lv;
#pragma unroll
  for (int j = 0; j < 4; j++) {
    bf16 h = (bf16)a[j];
    hv[j] = h;
    lv[j] = (bf16)(a[j] - (float)h);
  }
  size_t o = (size_t)tok * 1024 + t * 4;
  *(bf16x4*)(oh + o) = hv;
  *(bf16x4*)(ol + o) = lv;
}

// ---------------------------------------------------------------------------
// Routed expert GEMM (plain bf16): gather via tlist, atomicAdd scatter.
// ---------------------------------------------------------------------------
__global__ __launch_bounds__(256, 2) void gemm_moe(
    const bf16* __restrict__ A, const bf16* __restrict__ W,
    const int* __restrict__ tlist, const float* __restrict__ glist,
    const int* __restrict__ cnt, float* __restrict__ outp) {
  int e = blockIdx.z;
  int count = cnt[e];
  int m0 = blockIdx.y * 128;
  if (m0 >= count) return;
  int n0 = blockIdx.x * 128;
  const int* tl = tlist + e * 4096;
  const bf16* B = W + (size_t)e * 1024 * 1024;
  __shared__ __align__(16) bf16 As[4096], Bs[4096];
  int t = threadIdx.x, lane = t & 63, w = t >> 6;
  int i0 = t, i1 = t + 256;
  int ra = tl[m0 + (i0 >> 2)], rb = tl[m0 + (i1 >> 2)];
  const bf16* a0 = A + (size_t)ra * 1024 + (i0 & 3) * 8;
  const bf16* a1 = A + (size_t)rb * 1024 + (i1 & 3) * 8;
  const bf16* b0 = B + (size_t)(n0 + (i0 >> 2)) * 1024 + (i0 & 3) * 8;
  const bf16* b1 = B + (size_t)(n0 + (i1 >> 2)) * 1024 + (i1 & 3) * 8;
  int wm = (w >> 1) * 64, wn = (w & 1) * 64, lr = lane & 15, lq = lane >> 4;
  f32x4 acc[4][4];
#pragma unroll
  for (int i = 0; i < 4; i++)
#pragma unroll
    for (int j = 0; j < 4; j++) acc[i][j] = (f32x4){0.f, 0.f, 0.f, 0.f};
  for (int k0 = 0; k0 < 1024; k0 += 32) {
    __syncthreads();
    gld16(&As[i0 * 8], a0 + k0); gld16(&As[i1 * 8], a1 + k0);
    gld16(&Bs[i0 * 8], b0 + k0); gld16(&Bs[i1 * 8], b1 + k0);
    __syncthreads();
    bf16x8 af[4], bfr[4];
#pragma unroll
    for (int i = 0; i < 4; i++) {
      af[i] = *(const bf16x8*)&As[(wm + i * 16 + lr) * 32 + lq * 8];
      bfr[i] = *(const bf16x8*)&Bs[(wn + i * 16 + lr) * 32 + lq * 8];
    }
#pragma unroll
    for (int i = 0; i < 4; i++)
#pragma unroll
      for (int j = 0; j < 4; j++) acc[i][j] = MFMA(af[i], bfr[j], acc[i][j]);
  }
#pragma unroll
  for (int i = 0; i < 4; i++)
#pragma unroll
    for (int r = 0; r < 4; r++) {
      int slot = m0 + wm + i * 16 + lq * 4 + r;
      if (slot < count) {
        int tok = tl[slot];
        float gte = glist[e * 4096 + slot];
#pragma unroll
        for (int j = 0; j < 4; j++) {
          int col = n0 + wn + j * 16 + lr;
          atomicAdd(&outp[(size_t)tok * 1024 + col], gte * acc[i][j][r]);
        }
      }
    }
}

// ---------------------------------------------------------------------------
extern "C" void kernel_launch(void* const* d_in, const int* in_sizes, int n_in,
                              void* d_out, int out_size, void* d_ws, size_t ws_size,
                              hipStream_t stream) {
  (void)in_sizes; (void)n_in; (void)out_size; (void)ws_size;
  const float* x    = (const float*)d_in[0];
  const float* wq   = (const float*)d_in[1];
  const float* wk   = (const float*)d_in[2];
  const float* wv   = (const float*)d_in[3];
  const float* wo   = (const float*)d_in[4];
  const float* ln1g = (const float*)d_in[5];
  const float* ln1b = (const float*)d_in[6];
  const float* ln2g = (const float*)d_in[7];
  const float* ln2b = (const float*)d_in[8];
  const float* rw   = (const float*)d_in[9];
  const float* expw = (const float*)d_in[10];
  float* out = (float*)d_out;

  char* p = (char*)d_ws;
  auto take = [&](size_t bytes) -> char* {
    char* r = p;
    p += (bytes + 255) & ~(size_t)255;
    return r;
  };
  const size_t ND2 = 4096ull * 1024 * 2;  // bf16 [tokens][D]
  const size_t WD2 = 1024ull * 1024 * 2;  // bf16 [D][D]
  bf16* h_hi = (bf16*)take(ND2); bf16* h_lo = (bf16*)take(ND2);
  bf16* wqh = (bf16*)take(WD2); bf16* wql = (bf16*)take(WD2);
  bf16* wkh = (bf16*)take(WD2); bf16* wkl = (bf16*)take(WD2);
  bf16* wvh = (bf16*)take(WD2); bf16* wvl = (bf16*)take(WD2);
  bf16* woh = (bf16*)take(WD2); bf16* wol = (bf16*)take(WD2);
  bf16* q_hi = (bf16*)take(ND2); bf16* q_lo = (bf16*)take(ND2);
  bf16* k_hi = (bf16*)take(ND2); bf16* k_lo = (bf16*)take(ND2);
  bf16* vt_hi = (bf16*)take(ND2);
  bf16* a_hi = (bf16*)take(ND2); bf16* a_lo = (bf16*)take(ND2);
  bf16* h2h  = (bf16*)take(ND2);
  bf16* ewh  = (bf16*)take(8ull * 1024 * 1024 * 2);
  int*   tlist  = (int*)take(8ull * 4096 * 4);
  float* glist  = (float*)take(8ull * 4096 * 4);
  int*   cnt    = (int*)take(64);
  int*   reid   = (int*)take(4096 * 4);
  float2* rg    = (float2*)take(4096 * 8);
  float* O_acc  = (float*)take(4096ull * 1024 * 4);   // 16 MB
  float* L_acc  = (float*)take(4096ull * 16 * 4);     // 256 KB

  // 0: zero attention accumulators (graph-capturable memset nodes)
  hipMemsetAsync(O_acc, 0, 4096ull * 1024 * 4, stream);
  hipMemsetAsync(L_acc, 0, 4096ull * 16 * 4, stream);
  // 1: weight prep (all conversions fused)
  prep_weights<<<12288, 256, 0, stream>>>(wq, wk, wv, wo, expw, wqh, wql, wkh,
                                          wkl, wvh, wvl, woh, wol, ewh);
  // 2: LN1
  ln_split<<<4096, 256, 0, stream>>>(x, ln1g, ln1b, h_hi, h_lo);
  // 3a: Q/K projections (split-bf16, 3-pass)
  gemm_qk<<<dim3(8, 32, 2), 256, 0, stream>>>(h_hi, h_lo, wqh, wql, wkh, wkl,
                                              q_hi, q_lo, k_hi, k_lo);
  // 3b: V projection (plain bf16; transposed + quad-swizzled output)
  gemm_v<<<dim3(8, 32), 256, 0, stream>>>(h_hi, wvh, vt_hi);
  // 4: attention — 1280 key-chunk blocks, atomic combine
  attn_fused<<<dim3(32, 40), 256, 0, stream>>>(q_hi, q_lo, k_hi, k_lo, vt_hi,
                                               O_acc, L_acc);
  // 4b: normalize + emit split bf16
  attn_final<<<4096, 256, 0, stream>>>(O_acc, L_acc, a_hi, a_lo);
  // 5: WO + residual
  gemm_wo<<<dim3(8, 32), 256, 0, stream>>>(a_hi, a_lo, woh, wol, x, out);
  // 6: LN2 + router (fused, no atomics)
  ln2route<<<4096, 256, 0, stream>>>(out, ln2g, ln2b, rw, h2h, reid, rg);
  // 7: per-expert list compaction
  build_lists<<<8, 256, 0, stream>>>(reid, rg, tlist, glist, cnt);
  // 8: routed expert GEMM
  gemm_moe<<<dim3(8, 32, 8), 256, 0, stream>>>(h2h, ewh, tlist, glist, cnt,
                                               out);
}

// Round 7
// 414.978 us; speedup vs baseline: 1.0095x; 1.0095x over previous
//
#include <hip/hip_runtime.h>
#include <hip/hip_bf16.h>
#include <cstdint>

// ============================================================================
// MoE transformer layer, MI355X gfx950.
// Precision: upstream of the router (LN1, QK, attention scores, WO, LN2,
// logits) is ~fp32 via split-bf16 MFMA (3-pass); V path plain bf16; logits
// exact fp32; expert GEMM plain bf16; routed MoE via ballot-compacted lists.
// R11: key-chunked attention (1280 near-uniform blocks, LPT order), O/l pure
// sums combined via f32 atomicAdd into O_acc/L_acc. Occ 13.5 -> 25.7, attn
// 97.5 -> 80 us, but attn_final+memset+atomics masked the gain (total flat).
// R12:
//   - attn_final FUSED into gemm_wo: A-operand = O_acc f32 * (1/l) split to
//     hi/lo in registers, ds_write staging (same bytes as a_hi+a_lo pair).
//     Kernel + 32MB traffic removed.
//   - attn full-tile fast path (kt+64 <= qb, no wave masked — all but the
//     last 2 tiles of each q-row): both subtiles' QK chains issued together
//     (4 independent MFMA chains), zero mask VALU. Masked path unchanged.
//   - prep_weights: V weight lo-split dropped (V is plain bf16 since R10).
// ============================================================================

typedef __bf16 bf16;
typedef __bf16 bf16x8 __attribute__((ext_vector_type(8)));
typedef __bf16 bf16x4 __attribute__((ext_vector_type(4)));
typedef float f32x4 __attribute__((ext_vector_type(4)));
typedef float f32x16 __attribute__((ext_vector_type(16)));

#define MFMA(a, b, c) __builtin_amdgcn_mfma_f32_16x16x32_bf16(a, b, c, 0, 0, 0)
#define MFMA32(a, b, c) __builtin_amdgcn_mfma_f32_32x32x16_bf16(a, b, c, 0, 0, 0)

__device__ __forceinline__ void gld16(void* lds, const void* g) {
  __builtin_amdgcn_global_load_lds(
      (const __attribute__((address_space(1))) void*)g,
      (__attribute__((address_space(3))) void*)lds, 16, 0, 0);
}

// ---------------------------------------------------------------------------
// Fused weight prep: split wq/wk/wo into (hi,lo) bf16; wv + expw plain cvt.
// blocks 0..4095: q/k/v/o (1024 per weight); 4096..12287: expert cvt.
// ---------------------------------------------------------------------------
__global__ void prep_weights(const float* __restrict__ wq, const float* __restrict__ wk,
                             const float* __restrict__ wv, const float* __restrict__ wo,
                             const float* __restrict__ expw,
                             bf16* __restrict__ wqh, bf16* __restrict__ wql,
                             bf16* __restrict__ wkh, bf16* __restrict__ wkl,
                             bf16* __restrict__ wvh,
                             bf16* __restrict__ woh, bf16* __restrict__ wol,
                             bf16* __restrict__ ewh) {
  int bid = blockIdx.x;
  if (bid < 4096) {
    int wsel = bid >> 10;
    const float* src = wsel == 0 ? wq : wsel == 1 ? wk : wsel == 2 ? wv : wo;
    bf16* hi = wsel == 0 ? wqh : wsel == 1 ? wkh : wsel == 2 ? wvh : woh;
    bf16* lo = wsel == 0 ? wql : wsel == 1 ? wkl : wsel == 2 ? (bf16*)nullptr : wol;
    int i = ((bid & 1023) * 256 + threadIdx.x) * 4;
    float4 v = *(const float4*)(src + i);
    float a[4] = {v.x, v.y, v.z, v.w};
#pragma unroll
    for (int j = 0; j < 4; j++) {
      bf16 h = (bf16)a[j];
      hi[i + j] = h;
      if (wsel != 2) lo[i + j] = (bf16)(a[j] - (float)h);
    }
  } else {
    int i = ((bid - 4096) * 256 + threadIdx.x) * 4;
    float4 v = *(const float4*)(expw + i);
    ewh[i] = (bf16)v.x; ewh[i + 1] = (bf16)v.y;
    ewh[i + 2] = (bf16)v.z; ewh[i + 3] = (bf16)v.w;
  }
}

// ---------------------------------------------------------------------------
__global__ void ln_split(const float* __restrict__ x, const float* __restrict__ g,
                         const float* __restrict__ b, bf16* __restrict__ hi,
                         bf16* __restrict__ lo) {
  int tok = blockIdx.x, t = threadIdx.x;
  float4 v = ((const float4*)(x + (size_t)tok * 1024))[t];
  float s = v.x + v.y + v.z + v.w;
  float ss = v.x * v.x + v.y * v.y + v.z * v.z + v.w * v.w;
#pragma unroll
  for (int o = 1; o < 64; o <<= 1) { s += __shfl_xor(s, o); ss += __shfl_xor(ss, o); }
  __shared__ float red[8];
  int w = t >> 6, lane = t & 63;
  if (lane == 0) { red[w] = s; red[4 + w] = ss; }
  __syncthreads();
  s = red[0] + red[1] + red[2] + red[3];
  ss = red[4] + red[5] + red[6] + red[7];
  float mu = s * (1.f / 1024.f);
  float rstd = rsqrtf(ss * (1.f / 1024.f) - mu * mu + 1e-5f);
  float4 gv = ((const float4*)g)[t], bv = ((const float4*)b)[t];
  float y[4] = {(v.x - mu) * rstd * gv.x + bv.x, (v.y - mu) * rstd * gv.y + bv.y,
                (v.z - mu) * rstd * gv.z + bv.z, (v.w - mu) * rstd * gv.w + bv.w};
  size_t o = (size_t)tok * 1024 + t * 4;
#pragma unroll
  for (int j = 0; j < 4; j++) {
    bf16 h = (bf16)y[j];
    hi[o + j] = h;
    lo[o + j] = (bf16)(y[j] - (float)h);
  }
}

// ---------------------------------------------------------------------------
// Fused LN2 + router: exact fp32 logits from LDS h2, top-2, gates. No atomics.
// Also emits h2 bf16 (expert GEMM A operand).
// ---------------------------------------------------------------------------
__global__ void ln2route(const float* __restrict__ x1, const float* __restrict__ g,
                         const float* __restrict__ b, const float* __restrict__ rw,
                         bf16* __restrict__ h2h, int* __restrict__ eid,
                         float2* __restrict__ gout) {
  int tok = blockIdx.x, t = threadIdx.x;
  float4 v = ((const float4*)(x1 + (size_t)tok * 1024))[t];
  float s = v.x + v.y + v.z + v.w;
  float ss = v.x * v.x + v.y * v.y + v.z * v.z + v.w * v.w;
#pragma unroll
  for (int o = 1; o < 64; o <<= 1) { s += __shfl_xor(s, o); ss += __shfl_xor(ss, o); }
  __shared__ float red[8];
  __shared__ float h2s[1024];
  __shared__ float lg[8];
  int w = t >> 6, lane = t & 63;
  if (lane == 0) { red[w] = s; red[4 + w] = ss; }
  __syncthreads();
  s = red[0] + red[1] + red[2] + red[3];
  ss = red[4] + red[5] + red[6] + red[7];
  float mu = s * (1.f / 1024.f);
  float rstd = rsqrtf(ss * (1.f / 1024.f) - mu * mu + 1e-5f);
  float4 gv = ((const float4*)g)[t], bv = ((const float4*)b)[t];
  float4 y;
  y.x = (v.x - mu) * rstd * gv.x + bv.x;
  y.y = (v.y - mu) * rstd * gv.y + bv.y;
  y.z = (v.z - mu) * rstd * gv.z + bv.z;
  y.w = (v.w - mu) * rstd * gv.w + bv.w;
  ((float4*)h2s)[t] = y;
  size_t o = (size_t)tok * 1024 + t * 4;
  h2h[o] = (bf16)y.x; h2h[o + 1] = (bf16)y.y;
  h2h[o + 2] = (bf16)y.z; h2h[o + 3] = (bf16)y.w;
  __syncthreads();
  float a0 = 0.f, a1 = 0.f;
  const float4* r0 = (const float4*)(rw + (2 * w) * 1024);
  const float4* r1 = (const float4*)(rw + (2 * w + 1) * 1024);
#pragma unroll
  for (int it = 0; it < 4; it++) {
    float4 xv = ((const float4*)h2s)[lane + 64 * it];
    float4 w0 = r0[lane + 64 * it];
    float4 w1 = r1[lane + 64 * it];
    a0 += xv.x * w0.x + xv.y * w0.y + xv.z * w0.z + xv.w * w0.w;
    a1 += xv.x * w1.x + xv.y * w1.y + xv.z * w1.z + xv.w * w1.w;
  }
#pragma unroll
  for (int o2 = 1; o2 < 64; o2 <<= 1) {
    a0 += __shfl_xor(a0, o2);
    a1 += __shfl_xor(a1, o2);
  }
  if (lane == 0) { lg[2 * w] = a0; lg[2 * w + 1] = a1; }
  __syncthreads();
  if (t == 0) {
    int i0 = 0; float l0 = lg[0];
#pragma unroll
    for (int e = 1; e < 8; e++) if (lg[e] > l0) { l0 = lg[e]; i0 = e; }
    int i1 = -1; float l1 = -3e38f;
#pragma unroll
    for (int e = 0; e < 8; e++) if (e != i0 && lg[e] > l1) { l1 = lg[e]; i1 = e; }
    float e1 = __expf(l1 - l0);
    float den = 1.f + e1;
    eid[tok] = i0 | (i1 << 4);
    gout[tok] = make_float2(1.f / den, e1 / den);
  }
}

// ---------------------------------------------------------------------------
// Per-expert compaction: 8 blocks, ballot + popcount prefix scan, token order.
// ---------------------------------------------------------------------------
__global__ void build_lists(const int* __restrict__ eid,
                            const float2* __restrict__ gv,
                            int* __restrict__ tlist, float* __restrict__ glist,
                            int* __restrict__ cnt) {
  int e = blockIdx.x, t = threadIdx.x;
  int lane = t & 63, w = t >> 6;
  __shared__ int wt[4];
  int base = 0;
  for (int c = 0; c < 16; c++) {
    int tok = c * 256 + t;
    int pair = eid[tok];
    int e0 = pair & 15, e1 = pair >> 4;
    bool p = (e0 == e) || (e1 == e);
    float2 g2 = gv[tok];
    float gate = (e0 == e) ? g2.x : g2.y;
    unsigned long long m = __ballot(p);
    int rank = __popcll(m & ((1ull << lane) - 1ull));
    if (lane == 0) wt[w] = __popcll(m);
    __syncthreads();
    int off = base;
    for (int i = 0; i < w; i++) off += wt[i];
    if (p) {
      tlist[e * 4096 + off + rank] = tok;
      glist[e * 4096 + off + rank] = gate;
    }
    base += wt[0] + wt[1] + wt[2] + wt[3];
    __syncthreads();
  }
  if (t == 0) cnt[e] = base;
  int pad = (base + 127) & ~127;
  if (pad > 4096) pad = 4096;
  for (int i = base + t; i < pad; i += 256) {
    tlist[e * 4096 + i] = 0;
    glist[e * 4096 + i] = 0.f;
  }
}

// ---------------------------------------------------------------------------
// Split-bf16 NT GEMM core: C(128x128 fp32) = (Ah+Al) @ (Bh+Bl)^T, K=1024.
// ---------------------------------------------------------------------------
__device__ __forceinline__ void gemm_core_split(
    const bf16* __restrict__ Ah, const bf16* __restrict__ Al,
    const bf16* __restrict__ Bh, const bf16* __restrict__ Bl, int m0, int n0,
    f32x4 (&acc)[4][4]) {
  __shared__ __align__(16) bf16 As_h[4096], As_l[4096], Bs_h[4096], Bs_l[4096];
  int t = threadIdx.x, lane = t & 63, w = t >> 6;
  int i0 = t, i1 = t + 256;
  const bf16* a0h = Ah + (size_t)(m0 + (i0 >> 2)) * 1024 + (i0 & 3) * 8;
  const bf16* a1h = Ah + (size_t)(m0 + (i1 >> 2)) * 1024 + (i1 & 3) * 8;
  const bf16* a0l = Al + (size_t)(m0 + (i0 >> 2)) * 1024 + (i0 & 3) * 8;
  const bf16* a1l = Al + (size_t)(m0 + (i1 >> 2)) * 1024 + (i1 & 3) * 8;
  const bf16* b0h = Bh + (size_t)(n0 + (i0 >> 2)) * 1024 + (i0 & 3) * 8;
  const bf16* b1h = Bh + (size_t)(n0 + (i1 >> 2)) * 1024 + (i1 & 3) * 8;
  const bf16* b0l = Bl + (size_t)(n0 + (i0 >> 2)) * 1024 + (i0 & 3) * 8;
  const bf16* b1l = Bl + (size_t)(n0 + (i1 >> 2)) * 1024 + (i1 & 3) * 8;
  int wm = (w >> 1) * 64, wn = (w & 1) * 64;
  int lr = lane & 15, lq = lane >> 4;
  for (int k0 = 0; k0 < 1024; k0 += 32) {
    __syncthreads();
    gld16(&As_h[i0 * 8], a0h + k0); gld16(&As_h[i1 * 8], a1h + k0);
    gld16(&As_l[i0 * 8], a0l + k0); gld16(&As_l[i1 * 8], a1l + k0);
    gld16(&Bs_h[i0 * 8], b0h + k0); gld16(&Bs_h[i1 * 8], b1h + k0);
    gld16(&Bs_l[i0 * 8], b0l + k0); gld16(&Bs_l[i1 * 8], b1l + k0);
    __syncthreads();
    bf16x8 ah[4], al4[4], bh[4], bl4[4];
#pragma unroll
    for (int i = 0; i < 4; i++) {
      ah[i]  = *(const bf16x8*)&As_h[(wm + i * 16 + lr) * 32 + lq * 8];
      al4[i] = *(const bf16x8*)&As_l[(wm + i * 16 + lr) * 32 + lq * 8];
      bh[i]  = *(const bf16x8*)&Bs_h[(wn + i * 16 + lr) * 32 + lq * 8];
      bl4[i] = *(const bf16x8*)&Bs_l[(wn + i * 16 + lr) * 32 + lq * 8];
    }
#pragma unroll
    for (int i = 0; i < 4; i++)
#pragma unroll
      for (int j = 0; j < 4; j++) {
        f32x4 c = acc[i][j];
        c = MFMA(ah[i], bh[j], c);
        c = MFMA(ah[i], bl4[j], c);
        c = MFMA(al4[i], bh[j], c);
        acc[i][j] = c;
      }
  }
}

// Q/K projections (split-bf16, 3-pass). z==0 (Q) pre-scaled into exp2 domain.
__global__ __launch_bounds__(256, 2) void gemm_qk(
    const bf16* __restrict__ hh, const bf16* __restrict__ hl,
    const bf16* __restrict__ wqh, const bf16* __restrict__ wql,
    const bf16* __restrict__ wkh, const bf16* __restrict__ wkl,
    bf16* __restrict__ qh, bf16* __restrict__ ql, bf16* __restrict__ kh,
    bf16* __restrict__ kl) {
  int n0 = blockIdx.x * 128, m0 = blockIdx.y * 128, z = blockIdx.z;
  const bf16* Bh = z ? wkh : wqh;
  const bf16* Bl = z ? wkl : wql;
  f32x4 acc[4][4];
#pragma unroll
  for (int i = 0; i < 4; i++)
#pragma unroll
    for (int j = 0; j < 4; j++) acc[i][j] = (f32x4){0.f, 0.f, 0.f, 0.f};
  gemm_core_split(hh, hl, Bh, Bl, m0, n0, acc);
  int t = threadIdx.x, lane = t & 63, w = t >> 6;
  int wm = (w >> 1) * 64, wn = (w & 1) * 64, lr = lane & 15, lq = lane >> 4;
  bf16* Oh = z ? kh : qh;
  bf16* Ol = z ? kl : ql;
  float scale = z ? 1.0f : (0.125f * 1.44269504f);
#pragma unroll
  for (int i = 0; i < 4; i++)
#pragma unroll
    for (int j = 0; j < 4; j++)
#pragma unroll
      for (int r = 0; r < 4; r++) {
        size_t row = m0 + wm + i * 16 + lq * 4 + r;
        int col = n0 + wn + j * 16 + lr;
        float v = acc[i][j][r] * scale;
        bf16 h = (bf16)v;
        Oh[row * 1024 + col] = h;
        Ol[row * 1024 + col] = (bf16)(v - (float)h);
      }
}

// V projection: PLAIN bf16 single-pass. Output written DIRECTLY TRANSPOSED to
// vt[(b*16+head)*64+d][s] AND quad-swizzled within each 64-token chunk:
// physical quad = logical quad ^ (d&15). Attn's 8B sigma-reads alias at most
// 2-way (free) while gld16 staging stays linear.
__global__ __launch_bounds__(256, 2) void gemm_v(
    const bf16* __restrict__ A, const bf16* __restrict__ B,
    bf16* __restrict__ vth) {
  int n0 = blockIdx.x * 128, m0 = blockIdx.y * 128;
  __shared__ __align__(16) bf16 As[4096], Bs[4096];
  int t = threadIdx.x, lane = t & 63, w = t >> 6;
  int i0 = t, i1 = t + 256;
  const bf16* a0 = A + (size_t)(m0 + (i0 >> 2)) * 1024 + (i0 & 3) * 8;
  const bf16* a1 = A + (size_t)(m0 + (i1 >> 2)) * 1024 + (i1 & 3) * 8;
  const bf16* b0 = B + (size_t)(n0 + (i0 >> 2)) * 1024 + (i0 & 3) * 8;
  const bf16* b1 = B + (size_t)(n0 + (i1 >> 2)) * 1024 + (i1 & 3) * 8;
  int wm = (w >> 1) * 64, wn = (w & 1) * 64, lr = lane & 15, lq = lane >> 4;
  f32x4 acc[4][4];
#pragma unroll
  for (int i = 0; i < 4; i++)
#pragma unroll
    for (int j = 0; j < 4; j++) acc[i][j] = (f32x4){0.f, 0.f, 0.f, 0.f};
  for (int k0 = 0; k0 < 1024; k0 += 32) {
    __syncthreads();
    gld16(&As[i0 * 8], a0 + k0); gld16(&As[i1 * 8], a1 + k0);
    gld16(&Bs[i0 * 8], b0 + k0); gld16(&Bs[i1 * 8], b1 + k0);
    __syncthreads();
    bf16x8 af[4], bfr[4];
#pragma unroll
    for (int i = 0; i < 4; i++) {
      af[i] = *(const bf16x8*)&As[(wm + i * 16 + lr) * 32 + lq * 8];
      bfr[i] = *(const bf16x8*)&Bs[(wn + i * 16 + lr) * 32 + lq * 8];
    }
#pragma unroll
    for (int i = 0; i < 4; i++)
#pragma unroll
      for (int j = 0; j < 4; j++) acc[i][j] = MFMA(af[i], bfr[j], acc[i][j]);
  }
  int bb = m0 >> 11;           // batch index (128-row tile never crosses)
  int srow0 = m0 & 2047;
#pragma unroll
  for (int i = 0; i < 4; i++)
#pragma unroll
    for (int j = 0; j < 4; j++) {
      int col = n0 + wn + j * 16 + lr;  // dim in [0,1024)
      int head = col >> 6, d = col & 63;
      int s = srow0 + wm + i * 16 + lq * 4;  // quad-aligned token index
      // quad swizzle within 64-token chunk: pq = lq ^ (d&15)
      int ss = (s & ~63) | (((((s >> 2) & 15)) ^ (d & 15)) << 2);
      bf16x4 hv;
#pragma unroll
      for (int r = 0; r < 4; r++) hv[r] = (bf16)acc[i][j][r];
      size_t off = ((size_t)((bb * 16 + head) * 64 + d)) * 2048 + ss;
      *(bf16x4*)(vth + off) = hv;
    }
}

// ---------------------------------------------------------------------------
// WO projection + residual, with fused attention finalize (R12):
// A-operand = O_acc[tok][d] * (1/L_acc[tok][d>>6]), split hi/lo in registers,
// staged to LDS via ds_write (same bytes from HBM as the old a_hi/a_lo pair).
// out_f32 = x + (O/l) @ wo^T.
// ---------------------------------------------------------------------------
__global__ __launch_bounds__(256, 2) void gemm_wo(
    const float* __restrict__ Oacc, const float* __restrict__ Lacc,
    const bf16* __restrict__ bh, const bf16* __restrict__ bl,
    const float* __restrict__ resid, float* __restrict__ outp) {
  int n0 = blockIdx.x * 128, m0 = blockIdx.y * 128;
  __shared__ __align__(16) bf16 As_h[4096], As_l[4096], Bs_h[4096], Bs_l[4096];
  int t = threadIdx.x, lane = t & 63, w = t >> 6;
  int i0 = t, i1 = t + 256;
  int row0 = m0 + (i0 >> 2), row1 = m0 + (i1 >> 2);
  const float* a0 = Oacc + (size_t)row0 * 1024 + (i0 & 3) * 8;
  const float* a1 = Oacc + (size_t)row1 * 1024 + (i1 & 3) * 8;
  const bf16* b0h = bh + (size_t)(n0 + (i0 >> 2)) * 1024 + (i0 & 3) * 8;
  const bf16* b1h = bh + (size_t)(n0 + (i1 >> 2)) * 1024 + (i1 & 3) * 8;
  const bf16* b0l = bl + (size_t)(n0 + (i0 >> 2)) * 1024 + (i0 & 3) * 8;
  const bf16* b1l = bl + (size_t)(n0 + (i1 >> 2)) * 1024 + (i1 & 3) * 8;
  int wm = (w >> 1) * 64, wn = (w & 1) * 64;
  int lr = lane & 15, lq = lane >> 4;
  f32x4 acc[4][4];
#pragma unroll
  for (int i = 0; i < 4; i++)
#pragma unroll
    for (int j = 0; j < 4; j++) acc[i][j] = (f32x4){0.f, 0.f, 0.f, 0.f};
  for (int k0 = 0; k0 < 1024; k0 += 32) {
    __syncthreads();
    gld16(&Bs_h[i0 * 8], b0h + k0); gld16(&Bs_h[i1 * 8], b1h + k0);
    gld16(&Bs_l[i0 * 8], b0l + k0); gld16(&Bs_l[i1 * 8], b1l + k0);
    // A from O_acc: 8 f32 per slot, normalize by 1/l, split hi/lo, ds_write.
    int hd = k0 >> 6;   // head of all d touched this iter (d-span < 64)
    float linv0 = 1.f / Lacc[row0 * 16 + hd];
    float linv1 = 1.f / Lacc[row1 * 16 + hd];
    float4 va0 = *(const float4*)(a0 + k0);
    float4 vb0 = *(const float4*)(a0 + k0 + 4);
    float4 va1 = *(const float4*)(a1 + k0);
    float4 vb1 = *(const float4*)(a1 + k0 + 4);
    float f0[8] = {va0.x, va0.y, va0.z, va0.w, vb0.x, vb0.y, vb0.z, vb0.w};
    float f1[8] = {va1.x, va1.y, va1.z, va1.w, vb1.x, vb1.y, vb1.z, vb1.w};
    bf16x8 h0, l0, h1, l1;
#pragma unroll
    for (int j = 0; j < 8; j++) {
      float x0 = f0[j] * linv0;
      bf16 hh0 = (bf16)x0;
      h0[j] = hh0; l0[j] = (bf16)(x0 - (float)hh0);
      float x1 = f1[j] * linv1;
      bf16 hh1 = (bf16)x1;
      h1[j] = hh1; l1[j] = (bf16)(x1 - (float)hh1);
    }
    *(bf16x8*)&As_h[i0 * 8] = h0; *(bf16x8*)&As_l[i0 * 8] = l0;
    *(bf16x8*)&As_h[i1 * 8] = h1; *(bf16x8*)&As_l[i1 * 8] = l1;
    __syncthreads();
    bf16x8 ah[4], al4[4], bhf[4], bl4[4];
#pragma unroll
    for (int i = 0; i < 4; i++) {
      ah[i]  = *(const bf16x8*)&As_h[(wm + i * 16 + lr) * 32 + lq * 8];
      al4[i] = *(const bf16x8*)&As_l[(wm + i * 16 + lr) * 32 + lq * 8];
      bhf[i] = *(const bf16x8*)&Bs_h[(wn + i * 16 + lr) * 32 + lq * 8];
      bl4[i] = *(const bf16x8*)&Bs_l[(wn + i * 16 + lr) * 32 + lq * 8];
    }
#pragma unroll
    for (int i = 0; i < 4; i++)
#pragma unroll
      for (int j = 0; j < 4; j++) {
        f32x4 c = acc[i][j];
        c = MFMA(ah[i], bhf[j], c);
        c = MFMA(ah[i], bl4[j], c);
        c = MFMA(al4[i], bhf[j], c);
        acc[i][j] = c;
      }
  }
#pragma unroll
  for (int i = 0; i < 4; i++)
#pragma unroll
    for (int j = 0; j < 4; j++)
#pragma unroll
      for (int r = 0; r < 4; r++) {
        size_t row = m0 + wm + i * 16 + lq * 4 + r;
        int col = n0 + wn + j * 16 + lr;
        outp[row * 1024 + col] = resid[row * 1024 + col] + acc[i][j][r];
      }
}

// ---------------------------------------------------------------------------
// Attention subtile helpers (shared by full and masked paths).
// ---------------------------------------------------------------------------
__device__ __forceinline__ f32x16 qk_subtile(
    const bf16* __restrict__ Ks, const bf16* __restrict__ Kls, int keyr, int l5,
    const bf16x8 (&qfh)[4], const bf16x8 (&qfl)[4]) {
  f32x16 sA, sB;
#pragma unroll
  for (int r = 0; r < 16; r++) { sA[r] = 0.f; sB[r] = 0.f; }
#pragma unroll
  for (int c = 0; c < 4; c++) {
    int dg = ((2 * c + l5) ^ (keyr & 7)) * 8;
    bf16x8 kv = *(const bf16x8*)&Ks[keyr * 64 + dg];
    bf16x8 km = *(const bf16x8*)&Kls[keyr * 64 + dg];
    if (c < 2) {
      sA = MFMA32(kv, qfh[c], sA);
      sA = MFMA32(kv, qfl[c], sA);
      sA = MFMA32(km, qfh[c], sA);
    } else {
      sB = MFMA32(kv, qfh[c], sB);
      sB = MFMA32(kv, qfl[c], sB);
      sB = MFMA32(km, qfh[c], sB);
    }
  }
  return sA + sB;
}

__device__ __forceinline__ void exp_pack_pv(
    f32x16 sc, bool maskt, int kb0, int qg, int ktile,
    float& lsum, f32x16& O0, f32x16& O1,
    const bf16* __restrict__ Vs, int l31, int l5) {
  float pvv[16];
#pragma unroll
  for (int r = 0; r < 16; r++) {
    int cst = (r & 3) + 8 * (r >> 2);
    float sv = sc[r];
    if (maskt && (kb0 + cst > qg)) sv = -30000.f;
    float p = __builtin_amdgcn_exp2f(sv);
    pvv[r] = p;
    lsum += p;
  }
  uint32_t hw[4][2], lw[4][2];
#pragma unroll
  for (int o = 0; o < 4; o++)
#pragma unroll
    for (int j = 0; j < 2; j++) {
      int ra = 4 * o + 2 * j;
      bf16 h0 = (bf16)pvv[ra], h1 = (bf16)pvv[ra + 1];
      union { bf16 h[2]; uint32_t u; } ph, pl;
      ph.h[0] = h0; ph.h[1] = h1;
      pl.h[0] = (bf16)(pvv[ra] - (float)h0);
      pl.h[1] = (bf16)(pvv[ra + 1] - (float)h1);
      hw[o][j] = ph.u;
      lw[o][j] = pl.u;
    }
#pragma unroll
  for (int c2 = 0; c2 < 2; c2++) {
    union { uint32_t u[4]; bf16x8 v; } pa, plo;
    pa.u[0] = hw[2 * c2][0];     pa.u[1] = hw[2 * c2][1];
    pa.u[2] = hw[2 * c2 + 1][0]; pa.u[3] = hw[2 * c2 + 1][1];
    plo.u[0] = lw[2 * c2][0];     plo.u[1] = lw[2 * c2][1];
    plo.u[2] = lw[2 * c2 + 1][0]; plo.u[3] = lw[2 * c2 + 1][1];
    __builtin_amdgcn_s_setprio(1);
#pragma unroll
    for (int dtile = 0; dtile < 2; dtile++) {
      int d = dtile * 32 + l31;
      int pqA = ((8 * ktile + 4 * c2 + l5) ^ (d & 15)) * 4;
      union { bf16x4 q[2]; bf16x8 v; } vbu;
      vbu.q[0] = *(const bf16x4*)&Vs[d * 64 + pqA];
      vbu.q[1] = *(const bf16x4*)&Vs[d * 64 + (pqA ^ 8)];
      if (dtile == 0) {
        O0 = MFMA32(pa.v, vbu.v, O0);
        O0 = MFMA32(plo.v, vbu.v, O0);
      } else {
        O1 = MFMA32(pa.v, vbu.v, O1);
        O1 = MFMA32(plo.v, vbu.v, O1);
      }
    }
    __builtin_amdgcn_s_setprio(0);
  }
}

// ---------------------------------------------------------------------------
// Flash attention (R11 chunked + R12 full-tile fast path). Swapped QK^T
// (A=K,B=Q), register-P, own-quad sigma PV, plain-bf16 V (pre-swizzled),
// split QK accumulator, K/V double-buffered 2-phase staging.
// Grid = (32 hb, 40 chunk-items); O,l pure-sum partials -> atomicAdd.
// ---------------------------------------------------------------------------
__global__ __launch_bounds__(256, 3) void attn_fused(
    const bf16* __restrict__ qh, const bf16* __restrict__ ql,
    const bf16* __restrict__ kh, const bf16* __restrict__ kl,
    const bf16* __restrict__ vth,
    float* __restrict__ O_acc, float* __restrict__ L_acc) {
  const int S = 2048, D = 1024;
  static const unsigned char QTt[40] = {
      15, 15, 15, 15, 14, 14, 14, 13, 13, 13, 12, 12, 12, 11, 11, 11,
      10, 10, 9, 9, 8, 8, 7, 7, 6, 5, 4, 3,
      14, 10, 6, 2, 13, 9, 5, 1, 12, 8, 4, 0};
  static const unsigned char C0t[40] = {
      0, 8, 16, 24, 0, 8, 16, 0, 8, 16, 0, 8, 16, 0, 8, 16,
      0, 8, 0, 8, 0, 8, 0, 8, 0, 0, 0, 0,
      24, 16, 8, 0, 24, 16, 8, 0, 24, 16, 8, 0};
  static const unsigned char C1t[40] = {
      8, 16, 24, 32, 8, 16, 24, 8, 16, 24, 8, 16, 24, 8, 16, 24,
      8, 16, 8, 16, 8, 16, 8, 16, 8, 8, 8, 8,
      30, 22, 14, 6, 28, 20, 12, 4, 26, 18, 10, 2};
  int y = blockIdx.y;
  int qt = QTt[y];
  int tile0 = C0t[y], tile1 = C1t[y];
  int hb = blockIdx.x;
  int head = hb & 15, b = hb >> 4;
  int qb = qt * 128;
  int t = threadIdx.x, lane = t & 63, w = t >> 6;
  int l31 = lane & 31, l5 = lane >> 5;
  int base = b * S, hcol = head * 64;

  __shared__ __align__(16) bf16 Kh_s[2][4096], Kl_s[2][4096];  // [key64][d64] swz
  __shared__ __align__(16) bf16 Vh_s[2][4096];                 // [d64][key64] quad-swz

  bf16x8 qfh[4], qfl[4];
  {
    const bf16* p1 = qh + (size_t)(base + qb + w * 32 + l31) * D + hcol + l5 * 8;
    const bf16* p2 = ql + (size_t)(base + qb + w * 32 + l31) * D + hcol + l5 * 8;
#pragma unroll
    for (int c = 0; c < 4; c++) {
      qfh[c] = *(const bf16x8*)(p1 + 16 * c);
      qfl[c] = *(const bf16x8*)(p2 + 16 * c);
    }
  }
  f32x16 O0, O1;
  float lsum = 0.f;
#pragma unroll
  for (int r = 0; r < 16; r++) { O0[r] = 0.f; O1[r] = 0.f; }

  int r0 = t >> 3, p0 = t & 7;
  int g0 = p0 ^ (r0 & 7);
  const bf16* k0hp = kh + (size_t)(base + r0) * D + hcol + g0 * 8;
  const bf16* k1hp = kh + (size_t)(base + 32 + r0) * D + hcol + g0 * 8;
  const bf16* k0lp = kl + (size_t)(base + r0) * D + hcol + g0 * 8;
  const bf16* k1lp = kl + (size_t)(base + 32 + r0) * D + hcol + g0 * 8;
  const bf16* v0hp = vth + (size_t)(hb * 64 + r0) * 2048 + p0 * 8;
  const bf16* v1hp = vth + (size_t)(hb * 64 + 32 + r0) * 2048 + p0 * 8;

  int qwmin = qb + w * 32;

#define STAGE(kts, bb) do { \
    gld16(&Kh_s[bb][t * 8], k0hp + (size_t)(kts) * D); \
    gld16(&Kh_s[bb][2048 + t * 8], k1hp + (size_t)(kts) * D); \
    gld16(&Kl_s[bb][t * 8], k0lp + (size_t)(kts) * D); \
    gld16(&Kl_s[bb][2048 + t * 8], k1lp + (size_t)(kts) * D); \
    gld16(&Vh_s[bb][t * 8], v0hp + (kts)); \
    gld16(&Vh_s[bb][2048 + t * 8], v1hp + (kts)); \
  } while (0)

  STAGE(tile0 * 64, tile0 & 1);
  __syncthreads();

  for (int ti = tile0; ti < tile1; ++ti) {
    int kt = ti * 64;
    int bb = ti & 1;
    if (ti + 1 < tile1) STAGE((ti + 1) * 64, bb ^ 1);   // prefetch next tile
    const bf16* Ks = &Kh_s[bb][0];
    const bf16* Kls = &Kl_s[bb][0];
    const bf16* Vs = &Vh_s[bb][0];
    if (kt + 64 <= qb) {
      // ---- FULL tile: no wave masked; both subtiles' QK chains together ----
      __builtin_amdgcn_s_setprio(1);
      f32x16 sc0 = qk_subtile(Ks, Kls, l31, l5, qfh, qfl);
      f32x16 sc1 = qk_subtile(Ks, Kls, 32 + l31, l5, qfh, qfl);
      __builtin_amdgcn_s_setprio(0);
      exp_pack_pv(sc0, false, 0, 0, 0, lsum, O0, O1, Vs, l31, l5);
      exp_pack_pv(sc1, false, 0, 0, 1, lsum, O0, O1, Vs, l31, l5);
    } else if (kt <= qwmin + 31) {
      // ---- diagonal tiles: per-subtile with masking (rare) ----
      bool skip1 = (kt + 32 > qwmin + 31);
#pragma unroll
      for (int ktile = 0; ktile < 2; ktile++) {
        if (ktile == 1 && skip1) break;
        bool maskt = (kt + 32 * ktile + 31 > qwmin);
        __builtin_amdgcn_s_setprio(1);
        f32x16 sc = qk_subtile(Ks, Kls, ktile * 32 + l31, l5, qfh, qfl);
        __builtin_amdgcn_s_setprio(0);
        int kb0 = kt + 32 * ktile + 4 * l5;
        int qg = qwmin + l31;
        exp_pack_pv(sc, maskt, kb0, qg, ktile, lsum, O0, O1, Vs, l31, l5);
      }
    }
    __syncthreads();
  }
#undef STAGE
  // ---- epilogue: atomic combine of chunk partials (pure sums) ----
  if (tile0 * 64 <= qwmin + 31) {        // wave contributed something
    float ltot = lsum + __shfl_xor(lsum, 32);   // l(q=l31), both halves
    if (l5 == 0) {
      size_t tokq = (size_t)(base + qb + w * 32 + l31);
      atomicAdd(&L_acc[tokq * 16 + head], ltot);
    }
#pragma unroll
    for (int r = 0; r < 16; r++) {
      int qlocal = (r & 3) + 8 * (r >> 2) + 4 * l5;
      size_t tok = (size_t)(base + qb + w * 32 + qlocal);
      atomicAdd(&O_acc[tok * 1024 + hcol + l31], O0[r]);
      atomicAdd(&O_acc[tok * 1024 + hcol + 32 + l31], O1[r]);
    }
  }
}

// ---------------------------------------------------------------------------
// Routed expert GEMM (plain bf16): gather via tlist, atomicAdd scatter.
// ---------------------------------------------------------------------------
__global__ __launch_bounds__(256, 2) void gemm_moe(
    const bf16* __restrict__ A, const bf16* __restrict__ W,
    const int* __restrict__ tlist, const float* __restrict__ glist,
    const int* __restrict__ cnt, float* __restrict__ outp) {
  int e = blockIdx.z;
  int count = cnt[e];
  int m0 = blockIdx.y * 128;
  if (m0 >= count) return;
  int n0 = blockIdx.x * 128;
  const int* tl = tlist + e * 4096;
  const bf16* B = W + (size_t)e * 1024 * 1024;
  __shared__ __align__(16) bf16 As[4096], Bs[4096];
  int t = threadIdx.x, lane = t & 63, w = t >> 6;
  int i0 = t, i1 = t + 256;
  int ra = tl[m0 + (i0 >> 2)], rb = tl[m0 + (i1 >> 2)];
  const bf16* a0 = A + (size_t)ra * 1024 + (i0 & 3) * 8;
  const bf16* a1 = A + (size_t)rb * 1024 + (i1 & 3) * 8;
  const bf16* b0 = B + (size_t)(n0 + (i0 >> 2)) * 1024 + (i0 & 3) * 8;
  const bf16* b1 = B + (size_t)(n0 + (i1 >> 2)) * 1024 + (i1 & 3) * 8;
  int wm = (w >> 1) * 64, wn = (w & 1) * 64, lr = lane & 15, lq = lane >> 4;
  f32x4 acc[4][4];
#pragma unroll
  for (int i = 0; i < 4; i++)
#pragma unroll
    for (int j = 0; j < 4; j++) acc[i][j] = (f32x4){0.f, 0.f, 0.f, 0.f};
  for (int k0 = 0; k0 < 1024; k0 += 32) {
    __syncthreads();
    gld16(&As[i0 * 8], a0 + k0); gld16(&As[i1 * 8], a1 + k0);
    gld16(&Bs[i0 * 8], b0 + k0); gld16(&Bs[i1 * 8], b1 + k0);
    __syncthreads();
    bf16x8 af[4], bfr[4];
#pragma unroll
    for (int i = 0; i < 4; i++) {
      af[i] = *(const bf16x8*)&As[(wm + i * 16 + lr) * 32 + lq * 8];
      bfr[i] = *(const bf16x8*)&Bs[(wn + i * 16 + lr) * 32 + lq * 8];
    }
#pragma unroll
    for (int i = 0; i < 4; i++)
#pragma unroll
      for (int j = 0; j < 4; j++) acc[i][j] = MFMA(af[i], bfr[j], acc[i][j]);
  }
#pragma unroll
  for (int i = 0; i < 4; i++)
#pragma unroll
    for (int r = 0; r < 4; r++) {
      int slot = m0 + wm + i * 16 + lq * 4 + r;
      if (slot < count) {
        int tok = tl[slot];
        float gte = glist[e * 4096 + slot];
#pragma unroll
        for (int j = 0; j < 4; j++) {
          int col = n0 + wn + j * 16 + lr;
          atomicAdd(&outp[(size_t)tok * 1024 + col], gte * acc[i][j][r]);
        }
      }
    }
}

// ---------------------------------------------------------------------------
extern "C" void kernel_launch(void* const* d_in, const int* in_sizes, int n_in,
                              void* d_out, int out_size, void* d_ws, size_t ws_size,
                              hipStream_t stream) {
  (void)in_sizes; (void)n_in; (void)out_size; (void)ws_size;
  const float* x    = (const float*)d_in[0];
  const float* wq   = (const float*)d_in[1];
  const float* wk   = (const float*)d_in[2];
  const float* wv   = (const float*)d_in[3];
  const float* wo   = (const float*)d_in[4];
  const float* ln1g = (const float*)d_in[5];
  const float* ln1b = (const float*)d_in[6];
  const float* ln2g = (const float*)d_in[7];
  const float* ln2b = (const float*)d_in[8];
  const float* rw   = (const float*)d_in[9];
  const float* expw = (const float*)d_in[10];
  float* out = (float*)d_out;

  char* p = (char*)d_ws;
  auto take = [&](size_t bytes) -> char* {
    char* r = p;
    p += (bytes + 255) & ~(size_t)255;
    return r;
  };
  const size_t ND2 = 4096ull * 1024 * 2;  // bf16 [tokens][D]
  const size_t WD2 = 1024ull * 1024 * 2;  // bf16 [D][D]
  bf16* h_hi = (bf16*)take(ND2); bf16* h_lo = (bf16*)take(ND2);
  bf16* wqh = (bf16*)take(WD2); bf16* wql = (bf16*)take(WD2);
  bf16* wkh = (bf16*)take(WD2); bf16* wkl = (bf16*)take(WD2);
  bf16* wvh = (bf16*)take(WD2);
  bf16* woh = (bf16*)take(WD2); bf16* wol = (bf16*)take(WD2);
  bf16* q_hi = (bf16*)take(ND2); bf16* q_lo = (bf16*)take(ND2);
  bf16* k_hi = (bf16*)take(ND2); bf16* k_lo = (bf16*)take(ND2);
  bf16* vt_hi = (bf16*)take(ND2);
  bf16* h2h  = (bf16*)take(ND2);
  bf16* ewh  = (bf16*)take(8ull * 1024 * 1024 * 2);
  int*   tlist  = (int*)take(8ull * 4096 * 4);
  float* glist  = (float*)take(8ull * 4096 * 4);
  int*   cnt    = (int*)take(64);
  int*   reid   = (int*)take(4096 * 4);
  float2* rg    = (float2*)take(4096 * 8);
  float* O_acc  = (float*)take(4096ull * 1024 * 4);   // 16 MB
  float* L_acc  = (float*)take(4096ull * 16 * 4);     // 256 KB

  // 0: zero attention accumulators (graph-capturable memset nodes)
  hipMemsetAsync(O_acc, 0, 4096ull * 1024 * 4, stream);
  hipMemsetAsync(L_acc, 0, 4096ull * 16 * 4, stream);
  // 1: weight prep (all conversions fused)
  prep_weights<<<12288, 256, 0, stream>>>(wq, wk, wv, wo, expw, wqh, wql, wkh,
                                          wkl, wvh, woh, wol, ewh);
  // 2: LN1
  ln_split<<<4096, 256, 0, stream>>>(x, ln1g, ln1b, h_hi, h_lo);
  // 3a: Q/K projections (split-bf16, 3-pass)
  gemm_qk<<<dim3(8, 32, 2), 256, 0, stream>>>(h_hi, h_lo, wqh, wql, wkh, wkl,
                                              q_hi, q_lo, k_hi, k_lo);
  // 3b: V projection (plain bf16; transposed + quad-swizzled output)
  gemm_v<<<dim3(8, 32), 256, 0, stream>>>(h_hi, wvh, vt_hi);
  // 4: attention — 1280 key-chunk blocks, atomic combine, full-tile fast path
  attn_fused<<<dim3(32, 40), 256, 0, stream>>>(q_hi, q_lo, k_hi, k_lo, vt_hi,
                                               O_acc, L_acc);
  // 5: WO + residual (attention finalize fused into A-staging)
  gemm_wo<<<dim3(8, 32), 256, 0, stream>>>(O_acc, L_acc, woh, wol, x, out);
  // 6: LN2 + router (fused, no atomics)
  ln2route<<<4096, 256, 0, stream>>>(out, ln2g, ln2b, rw, h2h, reid, rg);
  // 7: per-expert list compaction
  build_lists<<<8, 256, 0, stream>>>(reid, rg, tlist, glist, cnt);
  // 8: routed expert GEMM
  gemm_moe<<<dim3(8, 32, 8), 256, 0, stream>>>(h2h, ewh, tlist, glist, cnt,
                                               out);
}

// Round 9
// 373.634 us; speedup vs baseline: 1.1212x; 1.1107x over previous
//
#include <hip/hip_runtime.h>
#include <hip/hip_bf16.h>
#include <cstdint>

// ============================================================================
// MoE transformer layer, MI355X gfx950.
// Precision: upstream of the router (LN1, QK, attention scores, WO, LN2,
// logits) is ~fp32 via split-bf16 MFMA (3-pass); V path plain bf16; logits
// exact fp32; expert GEMM plain bf16; routed MoE via ballot-compacted lists.
// R11: key-chunked attention (1280 blocks, LPT), O/l pure sums -> atomicAdd.
// R12: attn finalize fused into gemm_wo A-staging; attn full-tile fast path.
// R13 (GEMM occupancy — wo/v were 256 blocks = 1 block/CU = 1 wave/SIMD):
//   - gemm_qk + gemm_v merged into ONE kernel (z in {0,1,2}): 768 blocks =
//     3 blocks/CU (LDS 48KB, launch_bounds(256,3)). V blocks short, last.
//   - gemm_wo K-split x2 (z K-halves): 512 blocks = 2 blocks/CU. Partials
//     P0/P1 plain f32 stores (alias dead q/k buffers); residual+combine
//     folded into ln2route (out = x + P0 + P1 written there). No atomics.
//   - single memset over O_acc||L_acc.
//   - NOTE: plain-bf16 Q/K rejected by analysis: score err ~5e-3 -> logit
//     err ~1e-3 -> expected router top-2 flips O(1) across 4096 tokens ->
//     one flip = ~0.2 absmax = fail. Split score path is the minimum.
// (R13 resubmitted verbatim — previous bench died on container infra, no
//  signal was produced.)
// ============================================================================

typedef __bf16 bf16;
typedef __bf16 bf16x8 __attribute__((ext_vector_type(8)));
typedef __bf16 bf16x4 __attribute__((ext_vector_type(4)));
typedef float f32x4 __attribute__((ext_vector_type(4)));
typedef float f32x16 __attribute__((ext_vector_type(16)));

#define MFMA(a, b, c) __builtin_amdgcn_mfma_f32_16x16x32_bf16(a, b, c, 0, 0, 0)
#define MFMA32(a, b, c) __builtin_amdgcn_mfma_f32_32x32x16_bf16(a, b, c, 0, 0, 0)

__device__ __forceinline__ void gld16(void* lds, const void* g) {
  __builtin_amdgcn_global_load_lds(
      (const __attribute__((address_space(1))) void*)g,
      (__attribute__((address_space(3))) void*)lds, 16, 0, 0);
}

// ---------------------------------------------------------------------------
// Fused weight prep: split wq/wk/wo into (hi,lo) bf16; wv + expw plain cvt.
// ---------------------------------------------------------------------------
__global__ void prep_weights(const float* __restrict__ wq, const float* __restrict__ wk,
                             const float* __restrict__ wv, const float* __restrict__ wo,
                             const float* __restrict__ expw,
                             bf16* __restrict__ wqh, bf16* __restrict__ wql,
                             bf16* __restrict__ wkh, bf16* __restrict__ wkl,
                             bf16* __restrict__ wvh,
                             bf16* __restrict__ woh, bf16* __restrict__ wol,
                             bf16* __restrict__ ewh) {
  int bid = blockIdx.x;
  if (bid < 4096) {
    int wsel = bid >> 10;
    const float* src = wsel == 0 ? wq : wsel == 1 ? wk : wsel == 2 ? wv : wo;
    bf16* hi = wsel == 0 ? wqh : wsel == 1 ? wkh : wsel == 2 ? wvh : woh;
    bf16* lo = wsel == 0 ? wql : wsel == 1 ? wkl : wsel == 2 ? (bf16*)nullptr : wol;
    int i = ((bid & 1023) * 256 + threadIdx.x) * 4;
    float4 v = *(const float4*)(src + i);
    float a[4] = {v.x, v.y, v.z, v.w};
#pragma unroll
    for (int j = 0; j < 4; j++) {
      bf16 h = (bf16)a[j];
      hi[i + j] = h;
      if (wsel != 2) lo[i + j] = (bf16)(a[j] - (float)h);
    }
  } else {
    int i = ((bid - 4096) * 256 + threadIdx.x) * 4;
    float4 v = *(const float4*)(expw + i);
    ewh[i] = (bf16)v.x; ewh[i + 1] = (bf16)v.y;
    ewh[i + 2] = (bf16)v.z; ewh[i + 3] = (bf16)v.w;
  }
}

// ---------------------------------------------------------------------------
__global__ void ln_split(const float* __restrict__ x, const float* __restrict__ g,
                         const float* __restrict__ b, bf16* __restrict__ hi,
                         bf16* __restrict__ lo) {
  int tok = blockIdx.x, t = threadIdx.x;
  float4 v = ((const float4*)(x + (size_t)tok * 1024))[t];
  float s = v.x + v.y + v.z + v.w;
  float ss = v.x * v.x + v.y * v.y + v.z * v.z + v.w * v.w;
#pragma unroll
  for (int o = 1; o < 64; o <<= 1) { s += __shfl_xor(s, o); ss += __shfl_xor(ss, o); }
  __shared__ float red[8];
  int w = t >> 6, lane = t & 63;
  if (lane == 0) { red[w] = s; red[4 + w] = ss; }
  __syncthreads();
  s = red[0] + red[1] + red[2] + red[3];
  ss = red[4] + red[5] + red[6] + red[7];
  float mu = s * (1.f / 1024.f);
  float rstd = rsqrtf(ss * (1.f / 1024.f) - mu * mu + 1e-5f);
  float4 gv = ((const float4*)g)[t], bv = ((const float4*)b)[t];
  float y[4] = {(v.x - mu) * rstd * gv.x + bv.x, (v.y - mu) * rstd * gv.y + bv.y,
                (v.z - mu) * rstd * gv.z + bv.z, (v.w - mu) * rstd * gv.w + bv.w};
  size_t o = (size_t)tok * 1024 + t * 4;
#pragma unroll
  for (int j = 0; j < 4; j++) {
    bf16 h = (bf16)y[j];
    hi[o + j] = h;
    lo[o + j] = (bf16)(y[j] - (float)h);
  }
}

// ---------------------------------------------------------------------------
// Fused residual-combine + LN2 + router (R13): v = x + P0 + P1, written to
// out (residual stream pre-moe); exact fp32 logits, top-2, gates; h2 bf16.
// ---------------------------------------------------------------------------
__global__ void ln2route(const float* __restrict__ x0,
                         const float* __restrict__ P0, const float* __restrict__ P1,
                         const float* __restrict__ g, const float* __restrict__ b,
                         const float* __restrict__ rw, float* __restrict__ outp,
                         bf16* __restrict__ h2h, int* __restrict__ eid,
                         float2* __restrict__ gout) {
  int tok = blockIdx.x, t = threadIdx.x;
  float4 xv = ((const float4*)(x0 + (size_t)tok * 1024))[t];
  float4 p0 = ((const float4*)(P0 + (size_t)tok * 1024))[t];
  float4 p1 = ((const float4*)(P1 + (size_t)tok * 1024))[t];
  float4 v;
  v.x = xv.x + p0.x + p1.x;
  v.y = xv.y + p0.y + p1.y;
  v.z = xv.z + p0.z + p1.z;
  v.w = xv.w + p0.w + p1.w;
  ((float4*)(outp + (size_t)tok * 1024))[t] = v;   // residual stream pre-moe
  float s = v.x + v.y + v.z + v.w;
  float ss = v.x * v.x + v.y * v.y + v.z * v.z + v.w * v.w;
#pragma unroll
  for (int o = 1; o < 64; o <<= 1) { s += __shfl_xor(s, o); ss += __shfl_xor(ss, o); }
  __shared__ float red[8];
  __shared__ float h2s[1024];
  __shared__ float lg[8];
  int w = t >> 6, lane = t & 63;
  if (lane == 0) { red[w] = s; red[4 + w] = ss; }
  __syncthreads();
  s = red[0] + red[1] + red[2] + red[3];
  ss = red[4] + red[5] + red[6] + red[7];
  float mu = s * (1.f / 1024.f);
  float rstd = rsqrtf(ss * (1.f / 1024.f) - mu * mu + 1e-5f);
  float4 gv = ((const float4*)g)[t], bv = ((const float4*)b)[t];
  float4 y;
  y.x = (v.x - mu) * rstd * gv.x + bv.x;
  y.y = (v.y - mu) * rstd * gv.y + bv.y;
  y.z = (v.z - mu) * rstd * gv.z + bv.z;
  y.w = (v.w - mu) * rstd * gv.w + bv.w;
  ((float4*)h2s)[t] = y;
  size_t o = (size_t)tok * 1024 + t * 4;
  h2h[o] = (bf16)y.x; h2h[o + 1] = (bf16)y.y;
  h2h[o + 2] = (bf16)y.z; h2h[o + 3] = (bf16)y.w;
  __syncthreads();
  float a0 = 0.f, a1 = 0.f;
  const float4* r0 = (const float4*)(rw + (2 * w) * 1024);
  const float4* r1 = (const float4*)(rw + (2 * w + 1) * 1024);
#pragma unroll
  for (int it = 0; it < 4; it++) {
    float4 xv2 = ((const float4*)h2s)[lane + 64 * it];
    float4 w0 = r0[lane + 64 * it];
    float4 w1 = r1[lane + 64 * it];
    a0 += xv2.x * w0.x + xv2.y * w0.y + xv2.z * w0.z + xv2.w * w0.w;
    a1 += xv2.x * w1.x + xv2.y * w1.y + xv2.z * w1.z + xv2.w * w1.w;
  }
#pragma unroll
  for (int o2 = 1; o2 < 64; o2 <<= 1) {
    a0 += __shfl_xor(a0, o2);
    a1 += __shfl_xor(a1, o2);
  }
  if (lane == 0) { lg[2 * w] = a0; lg[2 * w + 1] = a1; }
  __syncthreads();
  if (t == 0) {
    int i0 = 0; float l0 = lg[0];
#pragma unroll
    for (int e = 1; e < 8; e++) if (lg[e] > l0) { l0 = lg[e]; i0 = e; }
    int i1 = -1; float l1 = -3e38f;
#pragma unroll
    for (int e = 0; e < 8; e++) if (e != i0 && lg[e] > l1) { l1 = lg[e]; i1 = e; }
    float e1 = __expf(l1 - l0);
    float den = 1.f + e1;
    eid[tok] = i0 | (i1 << 4);
    gout[tok] = make_float2(1.f / den, e1 / den);
  }
}

// ---------------------------------------------------------------------------
// Per-expert compaction: 8 blocks, ballot + popcount prefix scan, token order.
// ---------------------------------------------------------------------------
__global__ void build_lists(const int* __restrict__ eid,
                            const float2* __restrict__ gv,
                            int* __restrict__ tlist, float* __restrict__ glist,
                            int* __restrict__ cnt) {
  int e = blockIdx.x, t = threadIdx.x;
  int lane = t & 63, w = t >> 6;
  __shared__ int wt[4];
  int base = 0;
  for (int c = 0; c < 16; c++) {
    int tok = c * 256 + t;
    int pair = eid[tok];
    int e0 = pair & 15, e1 = pair >> 4;
    bool p = (e0 == e) || (e1 == e);
    float2 g2 = gv[tok];
    float gate = (e0 == e) ? g2.x : g2.y;
    unsigned long long m = __ballot(p);
    int rank = __popcll(m & ((1ull << lane) - 1ull));
    if (lane == 0) wt[w] = __popcll(m);
    __syncthreads();
    int off = base;
    for (int i = 0; i < w; i++) off += wt[i];
    if (p) {
      tlist[e * 4096 + off + rank] = tok;
      glist[e * 4096 + off + rank] = gate;
    }
    base += wt[0] + wt[1] + wt[2] + wt[3];
    __syncthreads();
  }
  if (t == 0) cnt[e] = base;
  int pad = (base + 127) & ~127;
  if (pad > 4096) pad = 4096;
  for (int i = base + t; i < pad; i += 256) {
    tlist[e * 4096 + i] = 0;
    glist[e * 4096 + i] = 0.f;
  }
}

// ---------------------------------------------------------------------------
// Split-bf16 NT GEMM core: C(128x128 fp32) = (Ah+Al) @ (Bh+Bl)^T, K=1024.
// ---------------------------------------------------------------------------
__device__ __forceinline__ void gemm_core_split(
    const bf16* __restrict__ Ah, const bf16* __restrict__ Al,
    const bf16* __restrict__ Bh, const bf16* __restrict__ Bl, int m0, int n0,
    f32x4 (&acc)[4][4]) {
  __shared__ __align__(16) bf16 As_h[4096], As_l[4096], Bs_h[4096], Bs_l[4096];
  int t = threadIdx.x, lane = t & 63, w = t >> 6;
  int i0 = t, i1 = t + 256;
  const bf16* a0h = Ah + (size_t)(m0 + (i0 >> 2)) * 1024 + (i0 & 3) * 8;
  const bf16* a1h = Ah + (size_t)(m0 + (i1 >> 2)) * 1024 + (i1 & 3) * 8;
  const bf16* a0l = Al + (size_t)(m0 + (i0 >> 2)) * 1024 + (i0 & 3) * 8;
  const bf16* a1l = Al + (size_t)(m0 + (i1 >> 2)) * 1024 + (i1 & 3) * 8;
  const bf16* b0h = Bh + (size_t)(n0 + (i0 >> 2)) * 1024 + (i0 & 3) * 8;
  const bf16* b1h = Bh + (size_t)(n0 + (i1 >> 2)) * 1024 + (i1 & 3) * 8;
  const bf16* b0l = Bl + (size_t)(n0 + (i0 >> 2)) * 1024 + (i0 & 3) * 8;
  const bf16* b1l = Bl + (size_t)(n0 + (i1 >> 2)) * 1024 + (i1 & 3) * 8;
  int wm = (w >> 1) * 64, wn = (w & 1) * 64;
  int lr = lane & 15, lq = lane >> 4;
  for (int k0 = 0; k0 < 1024; k0 += 32) {
    __syncthreads();
    gld16(&As_h[i0 * 8], a0h + k0); gld16(&As_h[i1 * 8], a1h + k0);
    gld16(&As_l[i0 * 8], a0l + k0); gld16(&As_l[i1 * 8], a1l + k0);
    gld16(&Bs_h[i0 * 8], b0h + k0); gld16(&Bs_h[i1 * 8], b1h + k0);
    gld16(&Bs_l[i0 * 8], b0l + k0); gld16(&Bs_l[i1 * 8], b1l + k0);
    __syncthreads();
    bf16x8 ah[4], al4[4], bh[4], bl4[4];
#pragma unroll
    for (int i = 0; i < 4; i++) {
      ah[i]  = *(const bf16x8*)&As_h[(wm + i * 16 + lr) * 32 + lq * 8];
      al4[i] = *(const bf16x8*)&As_l[(wm + i * 16 + lr) * 32 + lq * 8];
      bh[i]  = *(const bf16x8*)&Bs_h[(wn + i * 16 + lr) * 32 + lq * 8];
      bl4[i] = *(const bf16x8*)&Bs_l[(wn + i * 16 + lr) * 32 + lq * 8];
    }
#pragma unroll
    for (int i = 0; i < 4; i++)
#pragma unroll
      for (int j = 0; j < 4; j++) {
        f32x4 c = acc[i][j];
        c = MFMA(ah[i], bh[j], c);
        c = MFMA(ah[i], bl4[j], c);
        c = MFMA(al4[i], bh[j], c);
        acc[i][j] = c;
      }
  }
}

// ---------------------------------------------------------------------------
// Merged QKV projection (R13): z in {0,1} -> split 3-pass Q/K (Q pre-scaled
// into exp2 domain); z==2 -> plain bf16 V, written transposed + quad-swizzled
// (pq = lq ^ (d&15)). 768 blocks = 3 blocks/CU.
// ---------------------------------------------------------------------------
__global__ __launch_bounds__(256, 3) void gemm_qkv(
    const bf16* __restrict__ hh, const bf16* __restrict__ hl,
    const bf16* __restrict__ wqh, const bf16* __restrict__ wql,
    const bf16* __restrict__ wkh, const bf16* __restrict__ wkl,
    const bf16* __restrict__ wvh,
    bf16* __restrict__ qh, bf16* __restrict__ ql, bf16* __restrict__ kh,
    bf16* __restrict__ kl, bf16* __restrict__ vth) {
  int n0 = blockIdx.x * 128, m0 = blockIdx.y * 128, z = blockIdx.z;
  int t = threadIdx.x, lane = t & 63, w = t >> 6;
  int wm = (w >> 1) * 64, wn = (w & 1) * 64, lr = lane & 15, lq = lane >> 4;
  if (z < 2) {
    const bf16* Bh = z ? wkh : wqh;
    const bf16* Bl = z ? wkl : wql;
    f32x4 acc[4][4];
#pragma unroll
    for (int i = 0; i < 4; i++)
#pragma unroll
      for (int j = 0; j < 4; j++) acc[i][j] = (f32x4){0.f, 0.f, 0.f, 0.f};
    gemm_core_split(hh, hl, Bh, Bl, m0, n0, acc);
    bf16* Oh = z ? kh : qh;
    bf16* Ol = z ? kl : ql;
    float scale = z ? 1.0f : (0.125f * 1.44269504f);
#pragma unroll
    for (int i = 0; i < 4; i++)
#pragma unroll
      for (int j = 0; j < 4; j++)
#pragma unroll
        for (int r = 0; r < 4; r++) {
          size_t row = m0 + wm + i * 16 + lq * 4 + r;
          int col = n0 + wn + j * 16 + lr;
          float v = acc[i][j][r] * scale;
          bf16 h = (bf16)v;
          Oh[row * 1024 + col] = h;
          Ol[row * 1024 + col] = (bf16)(v - (float)h);
        }
  } else {
    __shared__ __align__(16) bf16 As[4096], Bs[4096];
    int i0 = t, i1 = t + 256;
    const bf16* a0 = hh + (size_t)(m0 + (i0 >> 2)) * 1024 + (i0 & 3) * 8;
    const bf16* a1 = hh + (size_t)(m0 + (i1 >> 2)) * 1024 + (i1 & 3) * 8;
    const bf16* b0 = wvh + (size_t)(n0 + (i0 >> 2)) * 1024 + (i0 & 3) * 8;
    const bf16* b1 = wvh + (size_t)(n0 + (i1 >> 2)) * 1024 + (i1 & 3) * 8;
    f32x4 acc[4][4];
#pragma unroll
    for (int i = 0; i < 4; i++)
#pragma unroll
      for (int j = 0; j < 4; j++) acc[i][j] = (f32x4){0.f, 0.f, 0.f, 0.f};
    for (int k0 = 0; k0 < 1024; k0 += 32) {
      __syncthreads();
      gld16(&As[i0 * 8], a0 + k0); gld16(&As[i1 * 8], a1 + k0);
      gld16(&Bs[i0 * 8], b0 + k0); gld16(&Bs[i1 * 8], b1 + k0);
      __syncthreads();
      bf16x8 af[4], bfr[4];
#pragma unroll
      for (int i = 0; i < 4; i++) {
        af[i] = *(const bf16x8*)&As[(wm + i * 16 + lr) * 32 + lq * 8];
        bfr[i] = *(const bf16x8*)&Bs[(wn + i * 16 + lr) * 32 + lq * 8];
      }
#pragma unroll
      for (int i = 0; i < 4; i++)
#pragma unroll
        for (int j = 0; j < 4; j++) acc[i][j] = MFMA(af[i], bfr[j], acc[i][j]);
    }
    int bb = m0 >> 11;           // batch index (128-row tile never crosses)
    int srow0 = m0 & 2047;
#pragma unroll
    for (int i = 0; i < 4; i++)
#pragma unroll
      for (int j = 0; j < 4; j++) {
        int col = n0 + wn + j * 16 + lr;  // dim in [0,1024)
        int head = col >> 6, d = col & 63;
        int s = srow0 + wm + i * 16 + lq * 4;  // quad-aligned token index
        int ss = (s & ~63) | (((((s >> 2) & 15)) ^ (d & 15)) << 2);
        bf16x4 hv;
#pragma unroll
        for (int r = 0; r < 4; r++) hv[r] = (bf16)acc[i][j][r];
        size_t off = ((size_t)((bb * 16 + head) * 64 + d)) * 2048 + ss;
        *(bf16x4*)(vth + off) = hv;
      }
  }
}

// ---------------------------------------------------------------------------
// WO projection, K-split x2 (R13), with fused attention finalize (R12):
// A-operand = O_acc[tok][d] * (1/L_acc[tok][d>>6]), split hi/lo in registers,
// staged via ds_write. Partial P_z = A[:, Kz] @ wo[:, Kz]^T, plain f32 store.
// z=0: K in [0,512); z=1: [512,1024). 512 blocks = 2 blocks/CU.
// ---------------------------------------------------------------------------
__global__ __launch_bounds__(256, 2) void gemm_wo(
    const float* __restrict__ Oacc, const float* __restrict__ Lacc,
    const bf16* __restrict__ bh, const bf16* __restrict__ bl,
    float* __restrict__ P0, float* __restrict__ P1) {
  int n0 = blockIdx.x * 128, m0 = blockIdx.y * 128, z = blockIdx.z;
  float* P = z ? P1 : P0;
  int kb = z * 512;
  __shared__ __align__(16) bf16 As_h[4096], As_l[4096], Bs_h[4096], Bs_l[4096];
  int t = threadIdx.x, lane = t & 63, w = t >> 6;
  int i0 = t, i1 = t + 256;
  int row0 = m0 + (i0 >> 2), row1 = m0 + (i1 >> 2);
  const float* a0 = Oacc + (size_t)row0 * 1024 + (i0 & 3) * 8;
  const float* a1 = Oacc + (size_t)row1 * 1024 + (i1 & 3) * 8;
  const bf16* b0h = bh + (size_t)(n0 + (i0 >> 2)) * 1024 + (i0 & 3) * 8;
  const bf16* b1h = bh + (size_t)(n0 + (i1 >> 2)) * 1024 + (i1 & 3) * 8;
  const bf16* b0l = bl + (size_t)(n0 + (i0 >> 2)) * 1024 + (i0 & 3) * 8;
  const bf16* b1l = bl + (size_t)(n0 + (i1 >> 2)) * 1024 + (i1 & 3) * 8;
  int wm = (w >> 1) * 64, wn = (w & 1) * 64;
  int lr = lane & 15, lq = lane >> 4;
  f32x4 acc[4][4];
#pragma unroll
  for (int i = 0; i < 4; i++)
#pragma unroll
    for (int j = 0; j < 4; j++) acc[i][j] = (f32x4){0.f, 0.f, 0.f, 0.f};
  for (int k0 = kb; k0 < kb + 512; k0 += 32) {
    __syncthreads();
    gld16(&Bs_h[i0 * 8], b0h + k0); gld16(&Bs_h[i1 * 8], b1h + k0);
    gld16(&Bs_l[i0 * 8], b0l + k0); gld16(&Bs_l[i1 * 8], b1l + k0);
    int hd = k0 >> 6;   // head of all d touched this iter (d-span < 64)
    float linv0 = 1.f / Lacc[row0 * 16 + hd];
    float linv1 = 1.f / Lacc[row1 * 16 + hd];
    float4 va0 = *(const float4*)(a0 + k0);
    float4 vb0 = *(const float4*)(a0 + k0 + 4);
    float4 va1 = *(const float4*)(a1 + k0);
    float4 vb1 = *(const float4*)(a1 + k0 + 4);
    float f0[8] = {va0.x, va0.y, va0.z, va0.w, vb0.x, vb0.y, vb0.z, vb0.w};
    float f1[8] = {va1.x, va1.y, va1.z, va1.w, vb1.x, vb1.y, vb1.z, vb1.w};
    bf16x8 h0, l0, h1, l1;
#pragma unroll
    for (int j = 0; j < 8; j++) {
      float x0 = f0[j] * linv0;
      bf16 hh0 = (bf16)x0;
      h0[j] = hh0; l0[j] = (bf16)(x0 - (float)hh0);
      float x1 = f1[j] * linv1;
      bf16 hh1 = (bf16)x1;
      h1[j] = hh1; l1[j] = (bf16)(x1 - (float)hh1);
    }
    *(bf16x8*)&As_h[i0 * 8] = h0; *(bf16x8*)&As_l[i0 * 8] = l0;
    *(bf16x8*)&As_h[i1 * 8] = h1; *(bf16x8*)&As_l[i1 * 8] = l1;
    __syncthreads();
    bf16x8 ah[4], al4[4], bhf[4], bl4[4];
#pragma unroll
    for (int i = 0; i < 4; i++) {
      ah[i]  = *(const bf16x8*)&As_h[(wm + i * 16 + lr) * 32 + lq * 8];
      al4[i] = *(const bf16x8*)&As_l[(wm + i * 16 + lr) * 32 + lq * 8];
      bhf[i] = *(const bf16x8*)&Bs_h[(wn + i * 16 + lr) * 32 + lq * 8];
      bl4[i] = *(const bf16x8*)&Bs_l[(wn + i * 16 + lr) * 32 + lq * 8];
    }
#pragma unroll
    for (int i = 0; i < 4; i++)
#pragma unroll
      for (int j = 0; j < 4; j++) {
        f32x4 c = acc[i][j];
        c = MFMA(ah[i], bhf[j], c);
        c = MFMA(ah[i], bl4[j], c);
        c = MFMA(al4[i], bhf[j], c);
        acc[i][j] = c;
      }
  }
#pragma unroll
  for (int i = 0; i < 4; i++)
#pragma unroll
    for (int j = 0; j < 4; j++)
#pragma unroll
      for (int r = 0; r < 4; r++) {
        size_t row = m0 + wm + i * 16 + lq * 4 + r;
        int col = n0 + wn + j * 16 + lr;
        P[row * 1024 + col] = acc[i][j][r];
      }
}

// ---------------------------------------------------------------------------
// Attention subtile helpers (shared by full and masked paths).
// ---------------------------------------------------------------------------
__device__ __forceinline__ f32x16 qk_subtile(
    const bf16* __restrict__ Ks, const bf16* __restrict__ Kls, int keyr, int l5,
    const bf16x8 (&qfh)[4], const bf16x8 (&qfl)[4]) {
  f32x16 sA, sB;
#pragma unroll
  for (int r = 0; r < 16; r++) { sA[r] = 0.f; sB[r] = 0.f; }
#pragma unroll
  for (int c = 0; c < 4; c++) {
    int dg = ((2 * c + l5) ^ (keyr & 7)) * 8;
    bf16x8 kv = *(const bf16x8*)&Ks[keyr * 64 + dg];
    bf16x8 km = *(const bf16x8*)&Kls[keyr * 64 + dg];
    if (c < 2) {
      sA = MFMA32(kv, qfh[c], sA);
      sA = MFMA32(kv, qfl[c], sA);
      sA = MFMA32(km, qfh[c], sA);
    } else {
      sB = MFMA32(kv, qfh[c], sB);
      sB = MFMA32(kv, qfl[c], sB);
      sB = MFMA32(km, qfh[c], sB);
    }
  }
  return sA + sB;
}

__device__ __forceinline__ void exp_pack_pv(
    f32x16 sc, bool maskt, int kb0, int qg, int ktile,
    float& lsum, f32x16& O0, f32x16& O1,
    const bf16* __restrict__ Vs, int l31, int l5) {
  float pvv[16];
#pragma unroll
  for (int r = 0; r < 16; r++) {
    int cst = (r & 3) + 8 * (r >> 2);
    float sv = sc[r];
    if (maskt && (kb0 + cst > qg)) sv = -30000.f;
    float p = __builtin_amdgcn_exp2f(sv);
    pvv[r] = p;
    lsum += p;
  }
  uint32_t hw[4][2], lw[4][2];
#pragma unroll
  for (int o = 0; o < 4; o++)
#pragma unroll
    for (int j = 0; j < 2; j++) {
      int ra = 4 * o + 2 * j;
      bf16 h0 = (bf16)pvv[ra], h1 = (bf16)pvv[ra + 1];
      union { bf16 h[2]; uint32_t u; } ph, pl;
      ph.h[0] = h0; ph.h[1] = h1;
      pl.h[0] = (bf16)(pvv[ra] - (float)h0);
      pl.h[1] = (bf16)(pvv[ra + 1] - (float)h1);
      hw[o][j] = ph.u;
      lw[o][j] = pl.u;
    }
#pragma unroll
  for (int c2 = 0; c2 < 2; c2++) {
    union { uint32_t u[4]; bf16x8 v; } pa, plo;
    pa.u[0] = hw[2 * c2][0];     pa.u[1] = hw[2 * c2][1];
    pa.u[2] = hw[2 * c2 + 1][0]; pa.u[3] = hw[2 * c2 + 1][1];
    plo.u[0] = lw[2 * c2][0];     plo.u[1] = lw[2 * c2][1];
    plo.u[2] = lw[2 * c2 + 1][0]; plo.u[3] = lw[2 * c2 + 1][1];
    __builtin_amdgcn_s_setprio(1);
#pragma unroll
    for (int dtile = 0; dtile < 2; dtile++) {
      int d = dtile * 32 + l31;
      int pqA = ((8 * ktile + 4 * c2 + l5) ^ (d & 15)) * 4;
      union { bf16x4 q[2]; bf16x8 v; } vbu;
      vbu.q[0] = *(const bf16x4*)&Vs[d * 64 + pqA];
      vbu.q[1] = *(const bf16x4*)&Vs[d * 64 + (pqA ^ 8)];
      if (dtile == 0) {
        O0 = MFMA32(pa.v, vbu.v, O0);
        O0 = MFMA32(plo.v, vbu.v, O0);
      } else {
        O1 = MFMA32(pa.v, vbu.v, O1);
        O1 = MFMA32(plo.v, vbu.v, O1);
      }
    }
    __builtin_amdgcn_s_setprio(0);
  }
}

// ---------------------------------------------------------------------------
// Flash attention (R11 chunked + R12 full-tile fast path). Swapped QK^T
// (A=K,B=Q), register-P, own-quad sigma PV, plain-bf16 V (pre-swizzled),
// split QK accumulator, K/V double-buffered 2-phase staging.
// Grid = (32 hb, 40 chunk-items); O,l pure-sum partials -> atomicAdd.
// ---------------------------------------------------------------------------
__global__ __launch_bounds__(256, 3) void attn_fused(
    const bf16* __restrict__ qh, const bf16* __restrict__ ql,
    const bf16* __restrict__ kh, const bf16* __restrict__ kl,
    const bf16* __restrict__ vth,
    float* __restrict__ O_acc, float* __restrict__ L_acc) {
  const int S = 2048, D = 1024;
  static const unsigned char QTt[40] = {
      15, 15, 15, 15, 14, 14, 14, 13, 13, 13, 12, 12, 12, 11, 11, 11,
      10, 10, 9, 9, 8, 8, 7, 7, 6, 5, 4, 3,
      14, 10, 6, 2, 13, 9, 5, 1, 12, 8, 4, 0};
  static const unsigned char C0t[40] = {
      0, 8, 16, 24, 0, 8, 16, 0, 8, 16, 0, 8, 16, 0, 8, 16,
      0, 8, 0, 8, 0, 8, 0, 8, 0, 0, 0, 0,
      24, 16, 8, 0, 24, 16, 8, 0, 24, 16, 8, 0};
  static const unsigned char C1t[40] = {
      8, 16, 24, 32, 8, 16, 24, 8, 16, 24, 8, 16, 24, 8, 16, 24,
      8, 16, 8, 16, 8, 16, 8, 16, 8, 8, 8, 8,
      30, 22, 14, 6, 28, 20, 12, 4, 26, 18, 10, 2};
  int y = blockIdx.y;
  int qt = QTt[y];
  int tile0 = C0t[y], tile1 = C1t[y];
  int hb = blockIdx.x;
  int head = hb & 15, b = hb >> 4;
  int qb = qt * 128;
  int t = threadIdx.x, lane = t & 63, w = t >> 6;
  int l31 = lane & 31, l5 = lane >> 5;
  int base = b * S, hcol = head * 64;

  __shared__ __align__(16) bf16 Kh_s[2][4096], Kl_s[2][4096];  // [key64][d64] swz
  __shared__ __align__(16) bf16 Vh_s[2][4096];                 // [d64][key64] quad-swz

  bf16x8 qfh[4], qfl[4];
  {
    const bf16* p1 = qh + (size_t)(base + qb + w * 32 + l31) * D + hcol + l5 * 8;
    const bf16* p2 = ql + (size_t)(base + qb + w * 32 + l31) * D + hcol + l5 * 8;
#pragma unroll
    for (int c = 0; c < 4; c++) {
      qfh[c] = *(const bf16x8*)(p1 + 16 * c);
      qfl[c] = *(const bf16x8*)(p2 + 16 * c);
    }
  }
  f32x16 O0, O1;
  float lsum = 0.f;
#pragma unroll
  for (int r = 0; r < 16; r++) { O0[r] = 0.f; O1[r] = 0.f; }

  int r0 = t >> 3, p0 = t & 7;
  int g0 = p0 ^ (r0 & 7);
  const bf16* k0hp = kh + (size_t)(base + r0) * D + hcol + g0 * 8;
  const bf16* k1hp = kh + (size_t)(base + 32 + r0) * D + hcol + g0 * 8;
  const bf16* k0lp = kl + (size_t)(base + r0) * D + hcol + g0 * 8;
  const bf16* k1lp = kl + (size_t)(base + 32 + r0) * D + hcol + g0 * 8;
  const bf16* v0hp = vth + (size_t)(hb * 64 + r0) * 2048 + p0 * 8;
  const bf16* v1hp = vth + (size_t)(hb * 64 + 32 + r0) * 2048 + p0 * 8;

  int qwmin = qb + w * 32;

#define STAGE(kts, bb) do { \
    gld16(&Kh_s[bb][t * 8], k0hp + (size_t)(kts) * D); \
    gld16(&Kh_s[bb][2048 + t * 8], k1hp + (size_t)(kts) * D); \
    gld16(&Kl_s[bb][t * 8], k0lp + (size_t)(kts) * D); \
    gld16(&Kl_s[bb][2048 + t * 8], k1lp + (size_t)(kts) * D); \
    gld16(&Vh_s[bb][t * 8], v0hp + (kts)); \
    gld16(&Vh_s[bb][2048 + t * 8], v1hp + (kts)); \
  } while (0)

  STAGE(tile0 * 64, tile0 & 1);
  __syncthreads();

  for (int ti = tile0; ti < tile1; ++ti) {
    int kt = ti * 64;
    int bb = ti & 1;
    if (ti + 1 < tile1) STAGE((ti + 1) * 64, bb ^ 1);   // prefetch next tile
    const bf16* Ks = &Kh_s[bb][0];
    const bf16* Kls = &Kl_s[bb][0];
    const bf16* Vs = &Vh_s[bb][0];
    if (kt + 64 <= qb) {
      // ---- FULL tile: no wave masked; both subtiles' QK chains together ----
      __builtin_amdgcn_s_setprio(1);
      f32x16 sc0 = qk_subtile(Ks, Kls, l31, l5, qfh, qfl);
      f32x16 sc1 = qk_subtile(Ks, Kls, 32 + l31, l5, qfh, qfl);
      __builtin_amdgcn_s_setprio(0);
      exp_pack_pv(sc0, false, 0, 0, 0, lsum, O0, O1, Vs, l31, l5);
      exp_pack_pv(sc1, false, 0, 0, 1, lsum, O0, O1, Vs, l31, l5);
    } else if (kt <= qwmin + 31) {
      // ---- diagonal tiles: per-subtile with masking (rare) ----
      bool skip1 = (kt + 32 > qwmin + 31);
#pragma unroll
      for (int ktile = 0; ktile < 2; ktile++) {
        if (ktile == 1 && skip1) break;
        bool maskt = (kt + 32 * ktile + 31 > qwmin);
        __builtin_amdgcn_s_setprio(1);
        f32x16 sc = qk_subtile(Ks, Kls, ktile * 32 + l31, l5, qfh, qfl);
        __builtin_amdgcn_s_setprio(0);
        int kb0 = kt + 32 * ktile + 4 * l5;
        int qg = qwmin + l31;
        exp_pack_pv(sc, maskt, kb0, qg, ktile, lsum, O0, O1, Vs, l31, l5);
      }
    }
    __syncthreads();
  }
#undef STAGE
  // ---- epilogue: atomic combine of chunk partials (pure sums) ----
  if (tile0 * 64 <= qwmin + 31) {        // wave contributed something
    float ltot = lsum + __shfl_xor(lsum, 32);   // l(q=l31), both halves
    if (l5 == 0) {
      size_t tokq = (size_t)(base + qb + w * 32 + l31);
      atomicAdd(&L_acc[tokq * 16 + head], ltot);
    }
#pragma unroll
    for (int r = 0; r < 16; r++) {
      int qlocal = (r & 3) + 8 * (r >> 2) + 4 * l5;
      size_t tok = (size_t)(base + qb + w * 32 + qlocal);
      atomicAdd(&O_acc[tok * 1024 + hcol + l31], O0[r]);
      atomicAdd(&O_acc[tok * 1024 + hcol + 32 + l31], O1[r]);
    }
  }
}

// ---------------------------------------------------------------------------
// Routed expert GEMM (plain bf16): gather via tlist, atomicAdd scatter.
// ---------------------------------------------------------------------------
__global__ __launch_bounds__(256, 2) void gemm_moe(
    const bf16* __restrict__ A, const bf16* __restrict__ W,
    const int* __restrict__ tlist, const float* __restrict__ glist,
    const int* __restrict__ cnt, float* __restrict__ outp) {
  int e = blockIdx.z;
  int count = cnt[e];
  int m0 = blockIdx.y * 128;
  if (m0 >= count) return;
  int n0 = blockIdx.x * 128;
  const int* tl = tlist + e * 4096;
  const bf16* B = W + (size_t)e * 1024 * 1024;
  __shared__ __align__(16) bf16 As[4096], Bs[4096];
  int t = threadIdx.x, lane = t & 63, w = t >> 6;
  int i0 = t, i1 = t + 256;
  int ra = tl[m0 + (i0 >> 2)], rb = tl[m0 + (i1 >> 2)];
  const bf16* a0 = A + (size_t)ra * 1024 + (i0 & 3) * 8;
  const bf16* a1 = A + (size_t)rb * 1024 + (i1 & 3) * 8;
  const bf16* b0 = B + (size_t)(n0 + (i0 >> 2)) * 1024 + (i0 & 3) * 8;
  const bf16* b1 = B + (size_t)(n0 + (i1 >> 2)) * 1024 + (i1 & 3) * 8;
  int wm = (w >> 1) * 64, wn = (w & 1) * 64, lr = lane & 15, lq = lane >> 4;
  f32x4 acc[4][4];
#pragma unroll
  for (int i = 0; i < 4; i++)
#pragma unroll
    for (int j = 0; j < 4; j++) acc[i][j] = (f32x4){0.f, 0.f, 0.f, 0.f};
  for (int k0 = 0; k0 < 1024; k0 += 32) {
    __syncthreads();
    gld16(&As[i0 * 8], a0 + k0); gld16(&As[i1 * 8], a1 + k0);
    gld16(&Bs[i0 * 8], b0 + k0); gld16(&Bs[i1 * 8], b1 + k0);
    __syncthreads();
    bf16x8 af[4], bfr[4];
#pragma unroll
    for (int i = 0; i < 4; i++) {
      af[i] = *(const bf16x8*)&As[(wm + i * 16 + lr) * 32 + lq * 8];
      bfr[i] = *(const bf16x8*)&Bs[(wn + i * 16 + lr) * 32 + lq * 8];
    }
#pragma unroll
    for (int i = 0; i < 4; i++)
#pragma unroll
      for (int j = 0; j < 4; j++) acc[i][j] = MFMA(af[i], bfr[j], acc[i][j]);
  }
#pragma unroll
  for (int i = 0; i < 4; i++)
#pragma unroll
    for (int r = 0; r < 4; r++) {
      int slot = m0 + wm + i * 16 + lq * 4 + r;
      if (slot < count) {
        int tok = tl[slot];
        float gte = glist[e * 4096 + slot];
#pragma unroll
        for (int j = 0; j < 4; j++) {
          int col = n0 + wn + j * 16 + lr;
          atomicAdd(&outp[(size_t)tok * 1024 + col], gte * acc[i][j][r]);
        }
      }
    }
}

// ---------------------------------------------------------------------------
extern "C" void kernel_launch(void* const* d_in, const int* in_sizes, int n_in,
                              void* d_out, int out_size, void* d_ws, size_t ws_size,
                              hipStream_t stream) {
  (void)in_sizes; (void)n_in; (void)out_size; (void)ws_size;
  const float* x    = (const float*)d_in[0];
  const float* wq   = (const float*)d_in[1];
  const float* wk   = (const float*)d_in[2];
  const float* wv   = (const float*)d_in[3];
  const float* wo   = (const float*)d_in[4];
  const float* ln1g = (const float*)d_in[5];
  const float* ln1b = (const float*)d_in[6];
  const float* ln2g = (const float*)d_in[7];
  const float* ln2b = (const float*)d_in[8];
  const float* rw   = (const float*)d_in[9];
  const float* expw = (const float*)d_in[10];
  float* out = (float*)d_out;

  char* p = (char*)d_ws;
  auto take = [&](size_t bytes) -> char* {
    char* r = p;
    p += (bytes + 255) & ~(size_t)255;
    return r;
  };
  const size_t ND2 = 4096ull * 1024 * 2;  // bf16 [tokens][D]
  const size_t WD2 = 1024ull * 1024 * 2;  // bf16 [D][D]
  bf16* h_hi = (bf16*)take(ND2); bf16* h_lo = (bf16*)take(ND2);
  bf16* wqh = (bf16*)take(WD2); bf16* wql = (bf16*)take(WD2);
  bf16* wkh = (bf16*)take(WD2); bf16* wkl = (bf16*)take(WD2);
  bf16* wvh = (bf16*)take(WD2);
  bf16* woh = (bf16*)take(WD2); bf16* wol = (bf16*)take(WD2);
  bf16* q_hi = (bf16*)take(ND2); bf16* q_lo = (bf16*)take(ND2);
  bf16* k_hi = (bf16*)take(ND2); bf16* k_lo = (bf16*)take(ND2);
  bf16* vt_hi = (bf16*)take(ND2);
  bf16* h2h  = (bf16*)take(ND2);
  bf16* ewh  = (bf16*)take(8ull * 1024 * 1024 * 2);
  int*   tlist  = (int*)take(8ull * 4096 * 4);
  float* glist  = (float*)take(8ull * 4096 * 4);
  int*   cnt    = (int*)take(64);
  int*   reid   = (int*)take(4096 * 4);
  float2* rg    = (float2*)take(4096 * 8);
  float* O_acc  = (float*)take(4096ull * 1024 * 4);   // 16 MB
  float* L_acc  = (float*)take(4096ull * 16 * 4);     // 256 KB (contiguous)
  // WO partials alias the (then-dead) Q/K buffers: q_hi||q_lo and k_hi||k_lo
  // are each contiguous 16 MB (ND2 is 256-aligned).
  float* P0 = (float*)q_hi;
  float* P1 = (float*)k_hi;

  // 0: zero attention accumulators (single contiguous memset)
  hipMemsetAsync(O_acc, 0, 4096ull * 1024 * 4 + 4096ull * 16 * 4, stream);
  // 1: weight prep (all conversions fused)
  prep_weights<<<12288, 256, 0, stream>>>(wq, wk, wv, wo, expw, wqh, wql, wkh,
                                          wkl, wvh, woh, wol, ewh);
  // 2: LN1
  ln_split<<<4096, 256, 0, stream>>>(x, ln1g, ln1b, h_hi, h_lo);
  // 3: merged QKV projection (768 blocks = 3/CU; V transposed + swizzled)
  gemm_qkv<<<dim3(8, 32, 3), 256, 0, stream>>>(h_hi, h_lo, wqh, wql, wkh, wkl,
                                               wvh, q_hi, q_lo, k_hi, k_lo,
                                               vt_hi);
  // 4: attention — 1280 key-chunk blocks, atomic combine, full-tile fast path
  attn_fused<<<dim3(32, 40), 256, 0, stream>>>(q_hi, q_lo, k_hi, k_lo, vt_hi,
                                               O_acc, L_acc);
  // 5: WO K-split x2 (512 blocks = 2/CU; finalize fused; partials to P0/P1,
  //    which alias q/k buffers — dead after attention)
  gemm_wo<<<dim3(8, 32, 2), 256, 0, stream>>>(O_acc, L_acc, woh, wol, P0, P1);
  // 6: residual combine + LN2 + router (out = x + P0 + P1 written here)
  ln2route<<<4096, 256, 0, stream>>>(x, P0, P1, ln2g, ln2b, rw, out, h2h,
                                     reid, rg);
  // 7: per-expert list compaction
  build_lists<<<8, 256, 0, stream>>>(reid, rg, tlist, glist, cnt);
  // 8: routed expert GEMM
  gemm_moe<<<dim3(8, 32, 8), 256, 0, stream>>>(h2h, ewh, tlist, glist, cnt,
                                               out);
}